// Round 17
// baseline (620.307 us; speedup 1.0000x reference)
//
#include <hip/hip_runtime.h>
#include <hip/hip_bf16.h>
#include <math.h>

#define D_MODEL 1024
#define D_STATE 16
#define D_INNER 2048
#define DT_RANK 64
#define BATCH   2
#define SEQLEN  2048
#define NPROJ   96   // DT_RANK + 2*D_STATE (logical)
#define XSTR    128  // padded x_dbl e-rows
#define LFLAT   (BATCH * SEQLEN)   // 4096, xdT row length
#define NCHUNK  16
#define CHUNK   128  // SEQLEN / NCHUNK
#define XKS     8    // x_dbl GEMM K-split

typedef __attribute__((ext_vector_type(8))) __bf16 bf16x8;
typedef __attribute__((ext_vector_type(4))) float f32x4;

__device__ __forceinline__ float silu_f(float x) { return x / (1.f + __expf(-x)); }

__device__ __forceinline__ void gload_lds16(const void* g, void* l) {
    __builtin_amdgcn_global_load_lds((const __attribute__((address_space(1))) void*)g,
                                     (__attribute__((address_space(3))) void*)l, 16, 0, 0);
}

// ---------------- bf16 MFMA NT GEMM: C[m,n] = sum_k A[m,k]*B[n,k] -------------
// 128x128 tile, BK=32, 4 waves. Bijective XCD swizzle on (y,x) flat id.
template<int RELU, int OUT_BF16>
__global__ __launch_bounds__(256) void gemm_bf16_k(
    const __bf16* __restrict__ A, const __bf16* __restrict__ B, void* __restrict__ Cv,
    int K, int lda, int ldb, int ldc, long long sA, long long sB, long long sC)
{
    __shared__ alignas(16) __bf16 As[128 * 32];
    __shared__ alignas(16) __bf16 Bs[128 * 32];
    const int bz = blockIdx.z;
    A += (long long)bz * sA;
    B += (long long)bz * sB;
    int nwg = gridDim.x * gridDim.y;
    int flat = blockIdx.y * gridDim.x + blockIdx.x;
    int swz = (nwg & 7) ? flat : ((flat & 7) * (nwg >> 3) + (flat >> 3));
    const int m0 = (swz / gridDim.x) * 128, n0 = (swz % gridDim.x) * 128;
    const int tid = threadIdx.x;
    const int lane = tid & 63;
    const int wv = tid >> 6;
    const int wr = wv >> 1, wc = wv & 1;

    f32x4 acc[4][4];
    #pragma unroll
    for (int i = 0; i < 4; ++i)
        #pragma unroll
        for (int j = 0; j < 4; ++j) acc[i][j] = (f32x4){0.f, 0.f, 0.f, 0.f};

    const int ko = (lane >> 4) * 8;
    const int fr = lane & 15;

    for (int k0 = 0; k0 < K; k0 += 32) {
        #pragma unroll
        for (int q = 0; q < 2; ++q) {
            int f = tid + q * 256;
            int row = f >> 2, c16 = f & 3;
            gload_lds16(A + (long long)(m0 + row) * lda + k0 + c16 * 8, As + f * 8);
            gload_lds16(B + (long long)(n0 + row) * ldb + k0 + c16 * 8, Bs + f * 8);
        }
        __syncthreads();
        bf16x8 a[4], b[4];
        #pragma unroll
        for (int i = 0; i < 4; ++i) {
            a[i] = *(const bf16x8*)(As + (wr * 64 + i * 16 + fr) * 32 + ko);
            b[i] = *(const bf16x8*)(Bs + (wc * 64 + i * 16 + fr) * 32 + ko);
        }
        #pragma unroll
        for (int i = 0; i < 4; ++i)
            #pragma unroll
            for (int j = 0; j < 4; ++j)
                acc[i][j] = __builtin_amdgcn_mfma_f32_16x16x32_bf16(a[i], b[j], acc[i][j], 0, 0, 0);
        __syncthreads();
    }

    #pragma unroll
    for (int i = 0; i < 4; ++i) {
        const int row = m0 + wr * 64 + i * 16 + (lane >> 4) * 4;
        #pragma unroll
        for (int j = 0; j < 4; ++j) {
            const int col = n0 + wc * 64 + j * 16 + fr;
            #pragma unroll
            for (int r = 0; r < 4; ++r) {
                float v = acc[i][j][r];
                if (RELU) v = fmaxf(v, 0.f);
                if (OUT_BF16)
                    ((__bf16*)Cv)[(long long)bz * sC + (long long)(row + r) * ldc + col] = (__bf16)v;
                else
                    ((float*)Cv)[(long long)bz * sC + (long long)(row + r) * ldc + col] = v;
            }
        }
    }
}

// ---------------- f32 -> bf16 pack (8 per thread) ----------------
__global__ void cvt_bf16_k(const float* __restrict__ in, __bf16* __restrict__ out, int n8) {
    int i = blockIdx.x * 256 + threadIdx.x;
    if (i >= n8) return;
    const f32x4* p = (const f32x4*)in + (long long)i * 2;
    f32x4 v0 = p[0], v1 = p[1];
    bf16x8 o;
    o[0] = (__bf16)v0[0]; o[1] = (__bf16)v0[1]; o[2] = (__bf16)v0[2]; o[3] = (__bf16)v0[3];
    o[4] = (__bf16)v1[0]; o[5] = (__bf16)v1[1]; o[6] = (__bf16)v1[2]; o[7] = (__bf16)v1[3];
    ((bf16x8*)out)[i] = o;
}

// ------------- fp32 NT/TN GEMM (dt GEMM; fused softplus; BT = B transposed) ---
// BT=1: B is [K][Ncols] with ldb = row stride (xdT layout).
template<int SOFTPLUS, int BT>
__global__ __launch_bounds__(256) void gemm_nt_k(
    const float* __restrict__ A, const float* __restrict__ B, float* __restrict__ C,
    const float* __restrict__ bias,
    int M, int N, int K, int lda, int ldb, int ldc,
    long long sA, long long sB, long long sC)
{
    __shared__ float As[16][68];
    __shared__ float Bs[16][68];
    const int bz = blockIdx.z;
    A += (long long)bz * sA; B += (long long)bz * sB; C += (long long)bz * sC;
    const int m0 = blockIdx.y * 64, n0 = blockIdx.x * 64;
    const int tid = threadIdx.x;
    const int lk = tid & 15, lr = tid >> 4;
    const int tx = tid & 15, ty = tid >> 4;
    float acc[4][4] = {};
    for (int k0 = 0; k0 < K; k0 += 16) {
        #pragma unroll
        for (int q = 0; q < 4; ++q) {
            int i = lr + q * 16;
            As[lk][i] = A[(long long)(m0 + i) * lda + k0 + lk];
        }
        if (BT) {
            #pragma unroll
            for (int q = 0; q < 4; ++q) {
                int row = (tid >> 6) + q * 4;      // k within BK
                int col = tid & 63;                // n
                Bs[row][col] = B[(long long)(k0 + row) * ldb + n0 + col];
            }
        } else {
            #pragma unroll
            for (int q = 0; q < 4; ++q) {
                int i = lr + q * 16;
                Bs[lk][i] = B[(long long)(n0 + i) * ldb + k0 + lk];
            }
        }
        __syncthreads();
        #pragma unroll
        for (int k = 0; k < 16; ++k) {
            float a[4], b[4];
            #pragma unroll
            for (int j = 0; j < 4; ++j) { a[j] = As[k][ty*4+j]; b[j] = Bs[k][tx*4+j]; }
            #pragma unroll
            for (int i = 0; i < 4; ++i)
                #pragma unroll
                for (int j = 0; j < 4; ++j) acc[i][j] += a[i] * b[j];
        }
        __syncthreads();
    }
    #pragma unroll
    for (int i = 0; i < 4; ++i) {
        const int m = m0 + ty * 4 + i;
        float bi = SOFTPLUS ? bias[m] : 0.f;
        #pragma unroll
        for (int j = 0; j < 4; ++j) {
            float v = acc[i][j];
            if (SOFTPLUS) {
                v += bi;
                v = fmaxf(v, 0.f) + log1pf(expf(-fabsf(v)));
            }
            C[(long long)m * ldc + n0 + tx*4 + j] = v;
        }
    }
}

// ---------------- Aneg = -exp(A_log) ----------------
__global__ void aneg_k(const float* __restrict__ A_log, float* __restrict__ Aneg) {
    int i = blockIdx.x * 256 + threadIdx.x;
    if (i < D_INNER * D_STATE) Aneg[i] = -expf(A_log[i]);
}

// ---------------- depthwise causal conv(4) + bias + SiLU, dual-layout out -----
__global__ __launch_bounds__(256) void conv_silu_k(const float* __restrict__ xz,
    const float* __restrict__ cw, const float* __restrict__ cb,
    float* __restrict__ u, __bf16* __restrict__ ut)
{
    __shared__ float tile[32][33];
    const int b = blockIdx.z;
    const int d0 = blockIdx.y * 32, l0 = blockIdx.x * 32;
    const int lx = threadIdx.x, dy = threadIdx.y;   // (32,8)
    #pragma unroll
    for (int j = 0; j < 4; ++j) {
        int d = d0 + dy + j * 8;
        const float* xi = xz + ((long long)b * 2 * D_INNER + d) * SEQLEN;
        int l = l0 + lx;
        float acc = cb[d];
        #pragma unroll
        for (int k = 0; k < 4; ++k) {
            int t = l + k - 3;
            if (t >= 0) acc += xi[t] * cw[d * 4 + k];
        }
        float v = silu_f(acc);
        u[((long long)b * D_INNER + d) * SEQLEN + l] = v;
        tile[dy + j * 8][lx] = v;
    }
    __syncthreads();
    #pragma unroll
    for (int j = 0; j < 4; ++j) {
        int l = l0 + dy + j * 8;
        ut[((long long)b * SEQLEN + l) * D_INNER + d0 + lx] = (__bf16)tile[lx][dy + j * 8];
    }
}

// ---------------- reduce XKS xdT partials -> xdT ----------------
__global__ void xdbl_red_k(const float* __restrict__ xpart, float* __restrict__ xdT) {
    int i = blockIdx.x * 256 + threadIdx.x;    // over 131072 float4s
    const f32x4* p = (const f32x4*)xpart;
    f32x4 s = p[i];
    #pragma unroll
    for (int ks = 1; ks < XKS; ++ks) {
        f32x4 v = p[(long long)ks * (XSTR * LFLAT / 4) + i];
        s.x += v.x; s.y += v.y; s.z += v.z; s.w += v.w;
    }
    ((f32x4*)xdT)[i] = s;
}

// ======== fused chunked selective scan: one block per chain ===================
// 256 threads = 4 waves; wave-local chunks (no barriers in main loops).
// xdT layout [e][b*L+l]: B/C rows are l-contiguous -> float4 prefetch.
__global__ __launch_bounds__(256) void scan_f_k(const float* __restrict__ delta,
    const float* __restrict__ u, const float* __restrict__ xdT,
    const float* __restrict__ Aneg, __bf16* __restrict__ y)
{
    __shared__ float combA[NCHUNK][16];
    __shared__ float combS[NCHUNK][16];
    __shared__ float sins[NCHUNK][16];
    __shared__ float lp[NCHUNK][16][17];
    const int tid = threadIdx.x;
    const int lane = tid & 63;
    const int n = lane & 15;
    const int c = (tid >> 6) * 4 + (lane >> 4);   // wave-local chunk id
    const int g = blockIdx.x;                     // chain id = b*D_INNER + d
    const int b = g >> 11, d = g & (D_INNER - 1);
    const float a = Aneg[d * D_STATE + n];
    const long long base = (long long)g * SEQLEN + c * CHUNK;
    const float4* dv = (const float4*)(delta + base);
    const float4* uv = (const float4*)(u + base);
    const long long lbase = (long long)b * SEQLEN + c * CHUNK;
    const float4* bv = (const float4*)(xdT + (long long)(DT_RANK + n) * LFLAT + lbase);
    const float4* cvv = (const float4*)(xdT + (long long)(DT_RANK + D_STATE + n) * LFLAT + lbase);

    // ---- pass 1: chunk-local scan from 0, accumulate A = prod dA ----
    float4 pd[4], pu[4], pb[4];
    #pragma unroll
    for (int i = 0; i < 4; ++i) { pd[i] = dv[i]; pu[i] = uv[i]; pb[i] = bv[i]; }

    float s = 0.f, ap = 1.f;
    for (int t0 = 0; t0 < CHUNK; t0 += 16) {
        float cd[16], cu[16], cB[16];
        #pragma unroll
        for (int i = 0; i < 4; ++i) {
            cd[4*i] = pd[i].x; cd[4*i+1] = pd[i].y; cd[4*i+2] = pd[i].z; cd[4*i+3] = pd[i].w;
            cu[4*i] = pu[i].x; cu[4*i+1] = pu[i].y; cu[4*i+2] = pu[i].z; cu[4*i+3] = pu[i].w;
            cB[4*i] = pb[i].x; cB[4*i+1] = pb[i].y; cB[4*i+2] = pb[i].z; cB[4*i+3] = pb[i].w;
        }
        if (t0 + 16 < CHUNK) {
            const int nb = (t0 >> 2) + 4;
            #pragma unroll
            for (int i = 0; i < 4; ++i) { pd[i] = dv[nb + i]; pu[i] = uv[nb + i]; pb[i] = bv[nb + i]; }
        }
        float dA[16], wB[16];
        #pragma unroll
        for (int i = 0; i < 16; ++i) {
            dA[i] = __expf(cd[i] * a);
            wB[i] = cd[i] * cu[i] * cB[i];
        }
        #pragma unroll
        for (int i = 0; i < 16; ++i) {
            s = dA[i] * s + wB[i];
            ap *= dA[i];
        }
    }
    combA[c][n] = ap;
    combS[c][n] = s;
    __syncthreads();

    // ---- combine: 16 threads do the serial 16-chunk prefix ----
    if (tid < 16) {
        float av[NCHUNK], sv[NCHUNK];
        #pragma unroll
        for (int cc = 0; cc < NCHUNK; ++cc) { av[cc] = combA[cc][tid]; sv[cc] = combS[cc][tid]; }
        float carry = 0.f;
        #pragma unroll
        for (int cc = 0; cc < NCHUNK; ++cc) {
            sins[cc][tid] = carry;
            carry = sv[cc] + av[cc] * carry;
        }
    }
    __syncthreads();

    // ---- pass 2: re-scan from sinit, emit y (no barriers: same-wave LDS) ----
    __bf16* yl = y + base;
    float4 pc[4];
    #pragma unroll
    for (int i = 0; i < 4; ++i) { pd[i] = dv[i]; pu[i] = uv[i]; pb[i] = bv[i]; pc[i] = cvv[i]; }

    s = sins[c][n];
    for (int t0 = 0; t0 < CHUNK; t0 += 16) {
        float cd[16], cu[16], cB[16], cC[16];
        #pragma unroll
        for (int i = 0; i < 4; ++i) {
            cd[4*i] = pd[i].x; cd[4*i+1] = pd[i].y; cd[4*i+2] = pd[i].z; cd[4*i+3] = pd[i].w;
            cu[4*i] = pu[i].x; cu[4*i+1] = pu[i].y; cu[4*i+2] = pu[i].z; cu[4*i+3] = pu[i].w;
            cB[4*i] = pb[i].x; cB[4*i+1] = pb[i].y; cB[4*i+2] = pb[i].z; cB[4*i+3] = pb[i].w;
            cC[4*i] = pc[i].x; cC[4*i+1] = pc[i].y; cC[4*i+2] = pc[i].z; cC[4*i+3] = pc[i].w;
        }
        if (t0 + 16 < CHUNK) {
            const int nb = (t0 >> 2) + 4;
            #pragma unroll
            for (int i = 0; i < 4; ++i) {
                pd[i] = dv[nb + i]; pu[i] = uv[nb + i];
                pb[i] = bv[nb + i]; pc[i] = cvv[nb + i];
            }
        }
        float dA[16], wB[16];
        #pragma unroll
        for (int i = 0; i < 16; ++i) {
            dA[i] = __expf(cd[i] * a);
            wB[i] = cd[i] * cu[i] * cB[i];
        }
        #pragma unroll
        for (int i = 0; i < 16; ++i) {
            s = dA[i] * s + wB[i];
            lp[c][n][i] = s * cC[i];
        }
        // same-wave transpose-reduce (lgkmcnt-ordered, no barrier)
        float v[16];
        #pragma unroll
        for (int j = 0; j < 16; ++j) v[j] = lp[c][j][n];
        float acc = 0.f;
        #pragma unroll
        for (int j = 0; j < 16; ++j) acc += v[j];
        yl[t0 + n] = (__bf16)acc;
    }
}

// ---------------- S[b,l] = sum_d Dp[d]*u[b,d,l] ----------------
__global__ void ssum_k(const float* __restrict__ u, const float* __restrict__ Dp,
                       float* __restrict__ S)
{
    int li = blockIdx.x * 256 + threadIdx.x;
    int c = blockIdx.y;
    int b = li >> 11, l = li & (SEQLEN - 1);
    const float* up = u + (long long)b * D_INNER * SEQLEN + l;
    float acc = 0.f;
    for (int d = c * 256; d < c * 256 + 256; ++d)
        acc += Dp[d] * up[(long long)d * SEQLEN];
    atomicAdd(&S[li], acc);
}

// ---------------- y=(y+Dp*u)*silu(z), transposed into ycat16[...,:2048] -------
__global__ __launch_bounds__(256) void ytrans_k(const __bf16* __restrict__ ysc,
    const float* __restrict__ u, const float* __restrict__ xz,
    const float* __restrict__ Dp, __bf16* __restrict__ ycat)
{
    __shared__ float tile[32][33];
    const int b = blockIdx.z;
    const int d0 = blockIdx.y * 32, l0 = blockIdx.x * 32;
    const int lx = threadIdx.x, dy = threadIdx.y;
    #pragma unroll
    for (int j = 0; j < 4; ++j) {
        int d = d0 + dy + j * 8;
        long long i  = ((long long)b * D_INNER + d) * SEQLEN + l0 + lx;
        long long iz = ((long long)b * 2 * D_INNER + D_INNER + d) * SEQLEN + l0 + lx;
        tile[dy + j * 8][lx] = ((float)ysc[i] + Dp[d] * u[i]) * silu_f(xz[iz]);
    }
    __syncthreads();
    #pragma unroll
    for (int j = 0; j < 4; ++j) {
        int l = l0 + dy + j * 8;
        ycat[((long long)b * SEQLEN + l) * (2 * D_INNER) + d0 + lx] = (__bf16)tile[lx][dy + j * 8];
    }
}

// ---------------- y_t -> ycat16[...,2048:]  (C from xdT, l-contiguous) --------
__global__ __launch_bounds__(256) void yt_k(const float* __restrict__ xdT,
    const float* __restrict__ Aneg, const float* __restrict__ S, __bf16* __restrict__ ycat)
{
    __shared__ float Cs[16][33];
    __shared__ float An[16][64];
    __shared__ float Sv[32];
    const int b = blockIdx.z;
    const int d0 = blockIdx.y * 64, l0 = blockIdx.x * 32;
    const int tid = threadIdx.x;
    for (int f = tid; f < 512; f += 256) {
        int n = f >> 5, l = f & 31;
        Cs[n][l] = xdT[(long long)(DT_RANK + D_STATE + n) * LFLAT + (long long)b * SEQLEN + l0 + l];
    }
    for (int f = tid; f < 1024; f += 256) {
        int n = f & 15, d = f >> 4;
        An[n][d] = Aneg[(d0 + d) * D_STATE + n];
    }
    if (tid < 32) Sv[tid] = S[b * SEQLEN + l0 + tid];
    __syncthreads();
    const int dx = tid & 63, lg = tid >> 6;
    #pragma unroll
    for (int j = 0; j < 8; ++j) {
        int l = lg * 8 + j;
        float acc = Sv[l];
        #pragma unroll
        for (int n = 0; n < 16; ++n) acc += Cs[n][l] * An[n][dx];
        ycat[((long long)b * SEQLEN + l0 + l) * (2 * D_INNER) + D_INNER + d0 + dx] = (__bf16)acc;
    }
}

extern "C" void kernel_launch(void* const* d_in, const int* in_sizes, int n_in,
                              void* d_out, int out_size, void* d_ws, size_t ws_size,
                              hipStream_t stream)
{
    const float* x      = (const float*)d_in[0];
    const float* W_in   = (const float*)d_in[1];
    const float* conv_w = (const float*)d_in[2];
    const float* conv_b = (const float*)d_in[3];
    const float* W_x    = (const float*)d_in[4];
    const float* W_dt   = (const float*)d_in[5];
    const float* b_dt   = (const float*)d_in[6];
    const float* A_log  = (const float*)d_in[7];
    const float* Dp     = (const float*)d_in[8];
    const float* W_out1 = (const float*)d_in[9];
    const float* W_out2 = (const float*)d_in[10];
    float* out = (float*)d_out;
    float* ws  = (float*)d_ws;

    // fp32 region
    float* xz    = ws;                    // 16777216
    float* u     = xz    + 16777216;      //  8388608
    float* xdT   = u     + 8388608;       //   524288 (128 e-rows x 4096 l)
    float* dtb   = xdT   + 524288;        //  8388608 (delta)
    float* Aneg  = dtb   + 8388608;       //    32768
    float* S     = Aneg  + 32768;         //     4096
    // bf16 buffers
    __bf16* ysc16  = (__bf16*)(S + 4096);          //  8388608 el (scan out, bf16)
    __bf16* ycat16 = ysc16 + 8388608;              // 16777216 el
    __bf16* h16    = ycat16 + 16777216;            //  8388608 el
    // overlays (regions dead at time of use)
    __bf16* W_in16  = (__bf16*)u;                  // before conv writes u
    __bf16* xb16    = W_in16 + 4194304;
    __bf16* Wout116 = (__bf16*)dtb;                // after scan reads dtb
    __bf16* Wout216 = Wout116 + 8388608;
    // u_t (bf16 [B*L][D_INNER], 16.8MB) inside ycat16 (33.5MB)
    __bf16* ut16  = ycat16;                        // 8388608 el
    // Wx bf16 padded [128][2048] inside h16 region (dead until out1 GEMM)
    __bf16* Wx16p = h16;                           // 262144 el
    // xdT K-split partials overlay dtb (dead until dt GEMM): 8*524288 floats
    float* xpart  = dtb;

    hipMemsetAsync(S, 0, 4096 * sizeof(float), stream);
    aneg_k<<<128, 256, 0, stream>>>(A_log, Aneg);

    // bf16 conversions for input GEMM
    cvt_bf16_k<<<2048, 256, 0, stream>>>(W_in, W_in16, 524288);
    cvt_bf16_k<<<2048, 256, 0, stream>>>(x, xb16, 524288);
    // W_x -> bf16 (96 rows), zero-pad rows 96..127
    cvt_bf16_k<<<96, 256, 0, stream>>>(W_x, Wx16p, 24576);
    hipMemsetAsync(Wx16p + 96 * D_INNER, 0, 32 * D_INNER * sizeof(__bf16), stream);

    // xz[b,e,l] = sum_d W_in[e,d] * x[b,l,d]   (M=4096, N=2048, K=1024)
    gemm_bf16_k<0, 0><<<dim3(16, 32, BATCH), 256, 0, stream>>>(
        W_in16, xb16, xz, D_MODEL, D_MODEL, D_MODEL, SEQLEN,
        0LL, (long long)SEQLEN * D_MODEL, (long long)4096 * SEQLEN);

    conv_silu_k<<<dim3(SEQLEN / 32, D_INNER / 32, BATCH), dim3(32, 8), 0, stream>>>(
        xz, conv_w, conv_b, u, ut16);

    // xdT[e][l_flat] = sum_d Wx[e,d] * u_t[l,d]  (M=128, N=4096, K-split=8)
    gemm_bf16_k<0, 0><<<dim3(32, 1, XKS), 256, 0, stream>>>(
        Wx16p, ut16, xpart, D_INNER / XKS, D_INNER, D_INNER, LFLAT,
        (long long)(D_INNER / XKS), (long long)(D_INNER / XKS),
        (long long)XSTR * LFLAT);
    xdbl_red_k<<<(XSTR * LFLAT / 4) / 256, 256, 0, stream>>>(xpart, xdT);

    // dt[b,d,l] = softplus(sum_r W_dt[d,r] * xdT[r][b*L+l] + b_dt[d])  (BT, fused)
    gemm_nt_k<1, 1><<<dim3(SEQLEN / 64, D_INNER / 64, BATCH), 256, 0, stream>>>(
        W_dt, xdT, dtb, b_dt, D_INNER, SEQLEN, DT_RANK, DT_RANK, LFLAT, SEQLEN,
        0LL, (long long)SEQLEN, (long long)D_INNER * SEQLEN);

    // fused chunked scan: one block per chain, bf16 y out
    scan_f_k<<<BATCH * D_INNER, 256, 0, stream>>>(dtb, u, xdT, Aneg, ysc16);

    // weight conversions for output GEMMs (dtb region dead now)
    cvt_bf16_k<<<4096, 256, 0, stream>>>(W_out1, Wout116, 1048576);
    cvt_bf16_k<<<1024, 256, 0, stream>>>(W_out2, Wout216, 262144);

    ssum_k<<<dim3((BATCH * SEQLEN) / 256, 8), 256, 0, stream>>>(u, Dp, S);

    ytrans_k<<<dim3(SEQLEN / 32, D_INNER / 32, BATCH), dim3(32, 8), 0, stream>>>(ysc16, u, xz, Dp, ycat16);

    yt_k<<<dim3(SEQLEN / 32, D_INNER / 64, BATCH), 256, 0, stream>>>(xdT, Aneg, S, ycat16);

    // h = relu(ycat @ W_out1^T) -> bf16   (M=4096, N=2048, K=4096)
    gemm_bf16_k<1, 1><<<dim3(16, 32, 1), 256, 0, stream>>>(
        ycat16, Wout116, h16, 2 * D_INNER, 2 * D_INNER, 2 * D_INNER, D_INNER,
        0LL, 0LL, 0LL);

    // out = h @ W_out2^T   (M=4096, N=1024, K=2048)
    gemm_bf16_k<0, 0><<<dim3(8, 32, 1), 256, 0, stream>>>(
        h16, Wout216, out, D_INNER, D_INNER, D_INNER, D_MODEL,
        0LL, 0LL, 0LL);
}

// Round 18
// 523.924 us; speedup vs baseline: 1.1840x; 1.1840x over previous
//
#include <hip/hip_runtime.h>
#include <hip/hip_bf16.h>
#include <math.h>

#define D_MODEL 1024
#define D_STATE 16
#define D_INNER 2048
#define DT_RANK 64
#define BATCH   2
#define SEQLEN  2048
#define NPROJ   96   // DT_RANK + 2*D_STATE (logical)
#define XSTR    128  // padded x_dbl row stride
#define NCHUNK  16
#define CHUNK   128  // SEQLEN / NCHUNK
#define XKS     8    // x_dbl GEMM K-split

typedef __attribute__((ext_vector_type(8))) __bf16 bf16x8;
typedef __attribute__((ext_vector_type(4))) float f32x4;

__device__ __forceinline__ float silu_f(float x) { return x / (1.f + __expf(-x)); }

__device__ __forceinline__ void gload_lds16(const void* g, void* l) {
    __builtin_amdgcn_global_load_lds((const __attribute__((address_space(1))) void*)g,
                                     (__attribute__((address_space(3))) void*)l, 16, 0, 0);
}

// ---------------- bf16 MFMA NT GEMM: C[m,n] = sum_k A[m,k]*B[n,k] -------------
// 128x128 tile, BK=32, 4 waves. Bijective XCD swizzle on (y,x) flat id.
template<int RELU, int OUT_BF16>
__global__ __launch_bounds__(256) void gemm_bf16_k(
    const __bf16* __restrict__ A, const __bf16* __restrict__ B, void* __restrict__ Cv,
    int K, int lda, int ldb, int ldc, long long sA, long long sB, long long sC)
{
    __shared__ alignas(16) __bf16 As[128 * 32];
    __shared__ alignas(16) __bf16 Bs[128 * 32];
    const int bz = blockIdx.z;
    A += (long long)bz * sA;
    B += (long long)bz * sB;
    int nwg = gridDim.x * gridDim.y;
    int flat = blockIdx.y * gridDim.x + blockIdx.x;
    int swz = (nwg & 7) ? flat : ((flat & 7) * (nwg >> 3) + (flat >> 3));
    const int m0 = (swz / gridDim.x) * 128, n0 = (swz % gridDim.x) * 128;
    const int tid = threadIdx.x;
    const int lane = tid & 63;
    const int wv = tid >> 6;
    const int wr = wv >> 1, wc = wv & 1;

    f32x4 acc[4][4];
    #pragma unroll
    for (int i = 0; i < 4; ++i)
        #pragma unroll
        for (int j = 0; j < 4; ++j) acc[i][j] = (f32x4){0.f, 0.f, 0.f, 0.f};

    const int ko = (lane >> 4) * 8;
    const int fr = lane & 15;

    for (int k0 = 0; k0 < K; k0 += 32) {
        #pragma unroll
        for (int q = 0; q < 2; ++q) {
            int f = tid + q * 256;
            int row = f >> 2, c16 = f & 3;
            gload_lds16(A + (long long)(m0 + row) * lda + k0 + c16 * 8, As + f * 8);
            gload_lds16(B + (long long)(n0 + row) * ldb + k0 + c16 * 8, Bs + f * 8);
        }
        __syncthreads();
        bf16x8 a[4], b[4];
        #pragma unroll
        for (int i = 0; i < 4; ++i) {
            a[i] = *(const bf16x8*)(As + (wr * 64 + i * 16 + fr) * 32 + ko);
            b[i] = *(const bf16x8*)(Bs + (wc * 64 + i * 16 + fr) * 32 + ko);
        }
        #pragma unroll
        for (int i = 0; i < 4; ++i)
            #pragma unroll
            for (int j = 0; j < 4; ++j)
                acc[i][j] = __builtin_amdgcn_mfma_f32_16x16x32_bf16(a[i], b[j], acc[i][j], 0, 0, 0);
        __syncthreads();
    }

    #pragma unroll
    for (int i = 0; i < 4; ++i) {
        const int row = m0 + wr * 64 + i * 16 + (lane >> 4) * 4;
        #pragma unroll
        for (int j = 0; j < 4; ++j) {
            const int col = n0 + wc * 64 + j * 16 + fr;
            #pragma unroll
            for (int r = 0; r < 4; ++r) {
                float v = acc[i][j][r];
                if (RELU) v = fmaxf(v, 0.f);
                if (OUT_BF16)
                    ((__bf16*)Cv)[(long long)bz * sC + (long long)(row + r) * ldc + col] = (__bf16)v;
                else
                    ((float*)Cv)[(long long)bz * sC + (long long)(row + r) * ldc + col] = v;
            }
        }
    }
}

// ---------------- f32 -> bf16 pack (8 per thread) ----------------
__global__ void cvt_bf16_k(const float* __restrict__ in, __bf16* __restrict__ out, int n8) {
    int i = blockIdx.x * 256 + threadIdx.x;
    if (i >= n8) return;
    const f32x4* p = (const f32x4*)in + (long long)i * 2;
    f32x4 v0 = p[0], v1 = p[1];
    bf16x8 o;
    o[0] = (__bf16)v0[0]; o[1] = (__bf16)v0[1]; o[2] = (__bf16)v0[2]; o[3] = (__bf16)v0[3];
    o[4] = (__bf16)v1[0]; o[5] = (__bf16)v1[1]; o[6] = (__bf16)v1[2]; o[7] = (__bf16)v1[3];
    ((bf16x8*)out)[i] = o;
}

// ---------------- generic fp32 NT GEMM (dt GEMM; fused softplus) --------------
template<int SOFTPLUS>
__global__ __launch_bounds__(256) void gemm_nt_k(
    const float* __restrict__ A, const float* __restrict__ B, float* __restrict__ C,
    const float* __restrict__ bias,
    int M, int N, int K, int lda, int ldb, int ldc,
    long long sA, long long sB, long long sC)
{
    __shared__ float As[16][68];
    __shared__ float Bs[16][68];
    const int bz = blockIdx.z;
    A += (long long)bz * sA; B += (long long)bz * sB; C += (long long)bz * sC;
    const int m0 = blockIdx.y * 64, n0 = blockIdx.x * 64;
    const int tid = threadIdx.x;
    const int lk = tid & 15, lr = tid >> 4;
    const int tx = tid & 15, ty = tid >> 4;
    float acc[4][4] = {};
    for (int k0 = 0; k0 < K; k0 += 16) {
        #pragma unroll
        for (int q = 0; q < 4; ++q) {
            int i = lr + q * 16;
            As[lk][i] = A[(long long)(m0 + i) * lda + k0 + lk];
            Bs[lk][i] = B[(long long)(n0 + i) * ldb + k0 + lk];
        }
        __syncthreads();
        #pragma unroll
        for (int k = 0; k < 16; ++k) {
            float a[4], b[4];
            #pragma unroll
            for (int j = 0; j < 4; ++j) { a[j] = As[k][ty*4+j]; b[j] = Bs[k][tx*4+j]; }
            #pragma unroll
            for (int i = 0; i < 4; ++i)
                #pragma unroll
                for (int j = 0; j < 4; ++j) acc[i][j] += a[i] * b[j];
        }
        __syncthreads();
    }
    #pragma unroll
    for (int i = 0; i < 4; ++i) {
        const int m = m0 + ty * 4 + i;
        float bi = SOFTPLUS ? bias[m] : 0.f;
        #pragma unroll
        for (int j = 0; j < 4; ++j) {
            float v = acc[i][j];
            if (SOFTPLUS) {
                v += bi;
                v = fmaxf(v, 0.f) + log1pf(expf(-fabsf(v)));
            }
            C[(long long)m * ldc + n0 + tx*4 + j] = v;
        }
    }
}

// ---------------- Aneg = -exp(A_log) ----------------
__global__ void aneg_k(const float* __restrict__ A_log, float* __restrict__ Aneg) {
    int i = blockIdx.x * 256 + threadIdx.x;
    if (i < D_INNER * D_STATE) Aneg[i] = -expf(A_log[i]);
}

// ---------------- depthwise causal conv(4) + bias + SiLU, dual-layout out -----
__global__ __launch_bounds__(256) void conv_silu_k(const float* __restrict__ xz,
    const float* __restrict__ cw, const float* __restrict__ cb,
    float* __restrict__ u, __bf16* __restrict__ ut)
{
    __shared__ float tile[32][33];
    const int b = blockIdx.z;
    const int d0 = blockIdx.y * 32, l0 = blockIdx.x * 32;
    const int lx = threadIdx.x, dy = threadIdx.y;   // (32,8)
    #pragma unroll
    for (int j = 0; j < 4; ++j) {
        int d = d0 + dy + j * 8;
        const float* xi = xz + ((long long)b * 2 * D_INNER + d) * SEQLEN;
        int l = l0 + lx;
        float acc = cb[d];
        #pragma unroll
        for (int k = 0; k < 4; ++k) {
            int t = l + k - 3;
            if (t >= 0) acc += xi[t] * cw[d * 4 + k];
        }
        float v = silu_f(acc);
        u[((long long)b * D_INNER + d) * SEQLEN + l] = v;
        tile[dy + j * 8][lx] = v;
    }
    __syncthreads();
    #pragma unroll
    for (int j = 0; j < 4; ++j) {
        int l = l0 + dy + j * 8;
        ut[((long long)b * SEQLEN + l) * D_INNER + d0 + lx] = (__bf16)tile[lx][dy + j * 8];
    }
}

// ---------------- reduce XKS x_dbl partials -> xdblp ----------------
__global__ void xdbl_red_k(const float* __restrict__ xpart, float* __restrict__ xdbl) {
    int i = blockIdx.x * 256 + threadIdx.x;
    const f32x4* p = (const f32x4*)xpart;
    f32x4 s = p[i];
    #pragma unroll
    for (int ks = 1; ks < XKS; ++ks) {
        f32x4 v = p[(long long)ks * (BATCH * SEQLEN * XSTR / 4) + i];
        s.x += v.x; s.y += v.y; s.z += v.z; s.w += v.w;
    }
    ((f32x4*)xdbl)[i] = s;
}

// ======== fused chunked selective scan: one block per chain ===================
// 256 threads = 4 waves; wave-local chunks (no barriers in main loops);
// B/C scalar loads are 16-lane contiguous (64B/chunk) from xdbl [l][128].
// y emitted bf16.
__global__ __launch_bounds__(256) void scan_f_k(const float* __restrict__ delta,
    const float* __restrict__ u, const float* __restrict__ xdbl,
    const float* __restrict__ Aneg, __bf16* __restrict__ y)
{
    __shared__ float combA[NCHUNK][16];
    __shared__ float combS[NCHUNK][16];
    __shared__ float sins[NCHUNK][16];
    __shared__ float lp[NCHUNK][16][17];
    const int tid = threadIdx.x;
    const int lane = tid & 63;
    const int n = lane & 15;
    const int c = (tid >> 6) * 4 + (lane >> 4);   // wave-local chunk id
    const int g = blockIdx.x;                     // chain id = b*D_INNER + d
    const int b = g >> 11, d = g & (D_INNER - 1);
    const float a = Aneg[d * D_STATE + n];
    const long long base = (long long)g * SEQLEN + c * CHUNK;
    const float4* dv = (const float4*)(delta + base);
    const float4* uv = (const float4*)(u + base);
    const float* xb = xdbl + ((long long)b * SEQLEN + c * CHUNK) * XSTR + DT_RANK + n;

    // ---- pass 1: chunk-local scan from 0, accumulate A = prod dA ----
    float4 pd[4], pu[4];
    float pB[16];
    #pragma unroll
    for (int i = 0; i < 4; ++i) { pd[i] = dv[i]; pu[i] = uv[i]; }
    #pragma unroll
    for (int i = 0; i < 16; ++i) pB[i] = xb[i * XSTR];

    float s = 0.f, ap = 1.f;
    for (int t0 = 0; t0 < CHUNK; t0 += 16) {
        float cd[16], cu[16], cB[16];
        #pragma unroll
        for (int i = 0; i < 4; ++i) {
            cd[4*i] = pd[i].x; cd[4*i+1] = pd[i].y; cd[4*i+2] = pd[i].z; cd[4*i+3] = pd[i].w;
            cu[4*i] = pu[i].x; cu[4*i+1] = pu[i].y; cu[4*i+2] = pu[i].z; cu[4*i+3] = pu[i].w;
        }
        #pragma unroll
        for (int i = 0; i < 16; ++i) cB[i] = pB[i];
        if (t0 + 16 < CHUNK) {
            const int nb = (t0 >> 2) + 4;
            #pragma unroll
            for (int i = 0; i < 4; ++i) { pd[i] = dv[nb + i]; pu[i] = uv[nb + i]; }
            const float* xn = xb + (t0 + 16) * XSTR;
            #pragma unroll
            for (int i = 0; i < 16; ++i) pB[i] = xn[i * XSTR];
        }
        float dA[16], wB[16];
        #pragma unroll
        for (int i = 0; i < 16; ++i) {
            dA[i] = __expf(cd[i] * a);
            wB[i] = cd[i] * cu[i] * cB[i];
        }
        #pragma unroll
        for (int i = 0; i < 16; ++i) {
            s = dA[i] * s + wB[i];
            ap *= dA[i];
        }
    }
    combA[c][n] = ap;
    combS[c][n] = s;
    __syncthreads();

    // ---- combine: 16 threads do the serial 16-chunk prefix ----
    if (tid < 16) {
        float av[NCHUNK], sv[NCHUNK];
        #pragma unroll
        for (int cc = 0; cc < NCHUNK; ++cc) { av[cc] = combA[cc][tid]; sv[cc] = combS[cc][tid]; }
        float carry = 0.f;
        #pragma unroll
        for (int cc = 0; cc < NCHUNK; ++cc) {
            sins[cc][tid] = carry;
            carry = sv[cc] + av[cc] * carry;
        }
    }
    __syncthreads();

    // ---- pass 2: re-scan from sinit, emit y bf16 (no barriers) ----
    __bf16* yl = y + base;
    float pC[16];
    #pragma unroll
    for (int i = 0; i < 4; ++i) { pd[i] = dv[i]; pu[i] = uv[i]; }
    #pragma unroll
    for (int i = 0; i < 16; ++i) { pB[i] = xb[i * XSTR]; pC[i] = xb[i * XSTR + D_STATE]; }

    s = sins[c][n];
    for (int t0 = 0; t0 < CHUNK; t0 += 16) {
        float cd[16], cu[16], cB[16], cC[16];
        #pragma unroll
        for (int i = 0; i < 4; ++i) {
            cd[4*i] = pd[i].x; cd[4*i+1] = pd[i].y; cd[4*i+2] = pd[i].z; cd[4*i+3] = pd[i].w;
            cu[4*i] = pu[i].x; cu[4*i+1] = pu[i].y; cu[4*i+2] = pu[i].z; cu[4*i+3] = pu[i].w;
        }
        #pragma unroll
        for (int i = 0; i < 16; ++i) { cB[i] = pB[i]; cC[i] = pC[i]; }
        if (t0 + 16 < CHUNK) {
            const int nb = (t0 >> 2) + 4;
            #pragma unroll
            for (int i = 0; i < 4; ++i) { pd[i] = dv[nb + i]; pu[i] = uv[nb + i]; }
            const float* xn = xb + (t0 + 16) * XSTR;
            #pragma unroll
            for (int i = 0; i < 16; ++i) { pB[i] = xn[i * XSTR]; pC[i] = xn[i * XSTR + D_STATE]; }
        }
        float dA[16], wB[16];
        #pragma unroll
        for (int i = 0; i < 16; ++i) {
            dA[i] = __expf(cd[i] * a);
            wB[i] = cd[i] * cu[i] * cB[i];
        }
        #pragma unroll
        for (int i = 0; i < 16; ++i) {
            s = dA[i] * s + wB[i];
            lp[c][n][i] = s * cC[i];
        }
        // same-wave transpose-reduce (lgkmcnt-ordered, no barrier)
        float v[16];
        #pragma unroll
        for (int j = 0; j < 16; ++j) v[j] = lp[c][j][n];
        float acc = 0.f;
        #pragma unroll
        for (int j = 0; j < 16; ++j) acc += v[j];
        yl[t0 + n] = (__bf16)acc;
    }
}

// ---------------- S[b,l] = sum_d Dp[d]*u[b,d,l] ----------------
__global__ void ssum_k(const float* __restrict__ u, const float* __restrict__ Dp,
                       float* __restrict__ S)
{
    int li = blockIdx.x * 256 + threadIdx.x;
    int c = blockIdx.y;
    int b = li >> 11, l = li & (SEQLEN - 1);
    const float* up = u + (long long)b * D_INNER * SEQLEN + l;
    float acc = 0.f;
    for (int d = c * 256; d < c * 256 + 256; ++d)
        acc += Dp[d] * up[(long long)d * SEQLEN];
    atomicAdd(&S[li], acc);
}

// ---------------- y=(y+Dp*u)*silu(z), transposed into ycat16[...,:2048] -------
__global__ __launch_bounds__(256) void ytrans_k(const __bf16* __restrict__ ysc,
    const float* __restrict__ u, const float* __restrict__ xz,
    const float* __restrict__ Dp, __bf16* __restrict__ ycat)
{
    __shared__ float tile[32][33];
    const int b = blockIdx.z;
    const int d0 = blockIdx.y * 32, l0 = blockIdx.x * 32;
    const int lx = threadIdx.x, dy = threadIdx.y;
    #pragma unroll
    for (int j = 0; j < 4; ++j) {
        int d = d0 + dy + j * 8;
        long long i  = ((long long)b * D_INNER + d) * SEQLEN + l0 + lx;
        long long iz = ((long long)b * 2 * D_INNER + D_INNER + d) * SEQLEN + l0 + lx;
        tile[dy + j * 8][lx] = ((float)ysc[i] + Dp[d] * u[i]) * silu_f(xz[iz]);
    }
    __syncthreads();
    #pragma unroll
    for (int j = 0; j < 4; ++j) {
        int l = l0 + dy + j * 8;
        ycat[((long long)b * SEQLEN + l) * (2 * D_INNER) + d0 + lx] = (__bf16)tile[lx][dy + j * 8];
    }
}

// ---------------- y_t -> ycat16[...,2048:] ----------------
__global__ __launch_bounds__(256) void yt_k(const float* __restrict__ xdbl,
    const float* __restrict__ Aneg, const float* __restrict__ S, __bf16* __restrict__ ycat)
{
    __shared__ float Cs[16][33];
    __shared__ float An[16][64];
    __shared__ float Sv[32];
    const int b = blockIdx.z;
    const int d0 = blockIdx.y * 64, l0 = blockIdx.x * 32;
    const int tid = threadIdx.x;
    for (int f = tid; f < 512; f += 256) {
        int n = f & 15, l = f >> 4;
        Cs[n][l] = xdbl[((long long)b * SEQLEN + l0 + l) * XSTR + DT_RANK + D_STATE + n];
    }
    for (int f = tid; f < 1024; f += 256) {
        int n = f & 15, d = f >> 4;
        An[n][d] = Aneg[(d0 + d) * D_STATE + n];
    }
    if (tid < 32) Sv[tid] = S[b * SEQLEN + l0 + tid];
    __syncthreads();
    const int dx = tid & 63, lg = tid >> 6;
    #pragma unroll
    for (int j = 0; j < 8; ++j) {
        int l = lg * 8 + j;
        float acc = Sv[l];
        #pragma unroll
        for (int n = 0; n < 16; ++n) acc += Cs[n][l] * An[n][dx];
        ycat[((long long)b * SEQLEN + l0 + l) * (2 * D_INNER) + D_INNER + d0 + dx] = (__bf16)acc;
    }
}

extern "C" void kernel_launch(void* const* d_in, const int* in_sizes, int n_in,
                              void* d_out, int out_size, void* d_ws, size_t ws_size,
                              hipStream_t stream)
{
    const float* x      = (const float*)d_in[0];
    const float* W_in   = (const float*)d_in[1];
    const float* conv_w = (const float*)d_in[2];
    const float* conv_b = (const float*)d_in[3];
    const float* W_x    = (const float*)d_in[4];
    const float* W_dt   = (const float*)d_in[5];
    const float* b_dt   = (const float*)d_in[6];
    const float* A_log  = (const float*)d_in[7];
    const float* Dp     = (const float*)d_in[8];
    const float* W_out1 = (const float*)d_in[9];
    const float* W_out2 = (const float*)d_in[10];
    float* out = (float*)d_out;
    float* ws  = (float*)d_ws;

    // fp32 region
    float* xz    = ws;                    // 16777216
    float* u     = xz    + 16777216;      //  8388608
    float* xdblp = u     + 8388608;       //   524288 (B*L x 128 padded)
    float* dtb   = xdblp + 524288;        //  8388608 (delta)
    float* Aneg  = dtb   + 8388608;       //    32768
    float* S     = Aneg  + 32768;         //     4096
    // bf16 buffers
    __bf16* ysc16  = (__bf16*)(S + 4096);          //  8388608 el (scan out, bf16)
    __bf16* ycat16 = ysc16 + 8388608;              // 16777216 el
    __bf16* h16    = ycat16 + 16777216;            //  8388608 el
    // overlays (regions dead at time of use)
    __bf16* W_in16  = (__bf16*)u;                  // before conv writes u
    __bf16* xb16    = W_in16 + 4194304;
    __bf16* Wout116 = (__bf16*)dtb;                // after scan reads dtb
    __bf16* Wout216 = Wout116 + 8388608;
    // u_t (bf16 [B*L][D_INNER], 16.8MB) inside ycat16 (33.5MB)
    __bf16* ut16  = ycat16;                        // 8388608 el
    // Wx bf16 padded [128][2048] inside h16 region (dead until out1 GEMM)
    __bf16* Wx16p = h16;                           // 262144 el
    // x_dbl K-split partials overlay dtb (dead until dt GEMM)
    float* xpart  = dtb;

    hipMemsetAsync(S, 0, 4096 * sizeof(float), stream);
    aneg_k<<<128, 256, 0, stream>>>(A_log, Aneg);

    // bf16 conversions for input GEMM
    cvt_bf16_k<<<2048, 256, 0, stream>>>(W_in, W_in16, 524288);
    cvt_bf16_k<<<2048, 256, 0, stream>>>(x, xb16, 524288);
    // W_x -> bf16 (96 rows), zero-pad rows 96..127
    cvt_bf16_k<<<96, 256, 0, stream>>>(W_x, Wx16p, 24576);
    hipMemsetAsync(Wx16p + 96 * D_INNER, 0, 32 * D_INNER * sizeof(__bf16), stream);

    // xz[b,e,l] = sum_d W_in[e,d] * x[b,l,d]   (M=4096, N=2048, K=1024)
    gemm_bf16_k<0, 0><<<dim3(16, 32, BATCH), 256, 0, stream>>>(
        W_in16, xb16, xz, D_MODEL, D_MODEL, D_MODEL, SEQLEN,
        0LL, (long long)SEQLEN * D_MODEL, (long long)4096 * SEQLEN);

    conv_silu_k<<<dim3(SEQLEN / 32, D_INNER / 32, BATCH), dim3(32, 8), 0, stream>>>(
        xz, conv_w, conv_b, u, ut16);

    // x_dbl partials: K-split=8 (z selects k-range via sA/sB), 256 blocks
    gemm_bf16_k<0, 0><<<dim3(1, 32, XKS), 256, 0, stream>>>(
        ut16, Wx16p, xpart, D_INNER / XKS, D_INNER, D_INNER, XSTR,
        (long long)(D_INNER / XKS), (long long)(D_INNER / XKS),
        (long long)BATCH * SEQLEN * XSTR);
    xdbl_red_k<<<(BATCH * SEQLEN * XSTR / 4) / 256, 256, 0, stream>>>(xpart, xdblp);

    // dt[b,d,l] = softplus(sum_r W_dt[d,r] * x_dbl[b,l,r] + b_dt[d])  (fused)
    gemm_nt_k<1><<<dim3(SEQLEN / 64, D_INNER / 64, BATCH), 256, 0, stream>>>(
        W_dt, xdblp, dtb, b_dt, D_INNER, SEQLEN, DT_RANK, DT_RANK, XSTR, SEQLEN,
        0LL, (long long)SEQLEN * XSTR, (long long)D_INNER * SEQLEN);

    // fused chunked scan: one block per chain, bf16 y out
    scan_f_k<<<BATCH * D_INNER, 256, 0, stream>>>(dtb, u, xdblp, Aneg, ysc16);

    // weight conversions for output GEMMs (dtb region dead now)
    cvt_bf16_k<<<4096, 256, 0, stream>>>(W_out1, Wout116, 1048576);
    cvt_bf16_k<<<1024, 256, 0, stream>>>(W_out2, Wout216, 262144);

    ssum_k<<<dim3((BATCH * SEQLEN) / 256, 8), 256, 0, stream>>>(u, Dp, S);

    ytrans_k<<<dim3(SEQLEN / 32, D_INNER / 32, BATCH), dim3(32, 8), 0, stream>>>(ysc16, u, xz, Dp, ycat16);

    yt_k<<<dim3(SEQLEN / 32, D_INNER / 64, BATCH), 256, 0, stream>>>(xdblp, Aneg, S, ycat16);

    // h = relu(ycat @ W_out1^T) -> bf16   (M=4096, N=2048, K=4096)
    gemm_bf16_k<1, 1><<<dim3(16, 32, 1), 256, 0, stream>>>(
        ycat16, Wout116, h16, 2 * D_INNER, 2 * D_INNER, 2 * D_INNER, D_INNER,
        0LL, 0LL, 0LL);

    // out = h @ W_out2^T   (M=4096, N=1024, K=2048)
    gemm_bf16_k<0, 0><<<dim3(8, 32, 1), 256, 0, stream>>>(
        h16, Wout216, out, D_INNER, D_INNER, D_INNER, D_MODEL,
        0LL, 0LL, 0LL);
}

// Round 20
// 487.649 us; speedup vs baseline: 1.2720x; 1.0744x over previous
//
#include <hip/hip_runtime.h>
#include <hip/hip_bf16.h>
#include <math.h>

#define D_MODEL 1024
#define D_STATE 16
#define D_INNER 2048
#define DT_RANK 64
#define BATCH   2
#define SEQLEN  2048
#define NPROJ   96   // DT_RANK + 2*D_STATE (logical)
#define XSTR    128  // padded x_dbl row stride
#define NCHUNK  16
#define CHUNK   128  // SEQLEN / NCHUNK
#define XKS     8    // x_dbl GEMM K-split

typedef __attribute__((ext_vector_type(8))) __bf16 bf16x8;
typedef __attribute__((ext_vector_type(4))) float f32x4;

__device__ __forceinline__ float silu_f(float x) { return x / (1.f + __expf(-x)); }

__device__ __forceinline__ void gload_lds16(const void* g, void* l) {
    __builtin_amdgcn_global_load_lds((const __attribute__((address_space(1))) void*)g,
                                     (__attribute__((address_space(3))) void*)l, 16, 0, 0);
}

// ---------------- bf16 MFMA NT GEMM: C[m,n] = sum_k A[m,k]*B[n,k] -------------
// 128x128 tile, BK=32, 4 waves. Bijective XCD swizzle on (y,x) flat id.
template<int RELU, int OUT_BF16>
__global__ __launch_bounds__(256) void gemm_bf16_k(
    const __bf16* __restrict__ A, const __bf16* __restrict__ B, void* __restrict__ Cv,
    int K, int lda, int ldb, int ldc, long long sA, long long sB, long long sC)
{
    __shared__ alignas(16) __bf16 As[128 * 32];
    __shared__ alignas(16) __bf16 Bs[128 * 32];
    const int bz = blockIdx.z;
    A += (long long)bz * sA;
    B += (long long)bz * sB;
    int nwg = gridDim.x * gridDim.y;
    int flat = blockIdx.y * gridDim.x + blockIdx.x;
    int swz = (nwg & 7) ? flat : ((flat & 7) * (nwg >> 3) + (flat >> 3));
    const int m0 = (swz / gridDim.x) * 128, n0 = (swz % gridDim.x) * 128;
    const int tid = threadIdx.x;
    const int lane = tid & 63;
    const int wv = tid >> 6;
    const int wr = wv >> 1, wc = wv & 1;

    f32x4 acc[4][4];
    #pragma unroll
    for (int i = 0; i < 4; ++i)
        #pragma unroll
        for (int j = 0; j < 4; ++j) acc[i][j] = (f32x4){0.f, 0.f, 0.f, 0.f};

    const int ko = (lane >> 4) * 8;
    const int fr = lane & 15;

    for (int k0 = 0; k0 < K; k0 += 32) {
        #pragma unroll
        for (int q = 0; q < 2; ++q) {
            int f = tid + q * 256;
            int row = f >> 2, c16 = f & 3;
            gload_lds16(A + (long long)(m0 + row) * lda + k0 + c16 * 8, As + f * 8);
            gload_lds16(B + (long long)(n0 + row) * ldb + k0 + c16 * 8, Bs + f * 8);
        }
        __syncthreads();
        bf16x8 a[4], b[4];
        #pragma unroll
        for (int i = 0; i < 4; ++i) {
            a[i] = *(const bf16x8*)(As + (wr * 64 + i * 16 + fr) * 32 + ko);
            b[i] = *(const bf16x8*)(Bs + (wc * 64 + i * 16 + fr) * 32 + ko);
        }
        #pragma unroll
        for (int i = 0; i < 4; ++i)
            #pragma unroll
            for (int j = 0; j < 4; ++j)
                acc[i][j] = __builtin_amdgcn_mfma_f32_16x16x32_bf16(a[i], b[j], acc[i][j], 0, 0, 0);
        __syncthreads();
    }

    #pragma unroll
    for (int i = 0; i < 4; ++i) {
        const int row = m0 + wr * 64 + i * 16 + (lane >> 4) * 4;
        #pragma unroll
        for (int j = 0; j < 4; ++j) {
            const int col = n0 + wc * 64 + j * 16 + fr;
            #pragma unroll
            for (int r = 0; r < 4; ++r) {
                float v = acc[i][j][r];
                if (RELU) v = fmaxf(v, 0.f);
                if (OUT_BF16)
                    ((__bf16*)Cv)[(long long)bz * sC + (long long)(row + r) * ldc + col] = (__bf16)v;
                else
                    ((float*)Cv)[(long long)bz * sC + (long long)(row + r) * ldc + col] = v;
            }
        }
    }
}

// ---------------- f32 -> bf16 pack (8 per thread) ----------------
__global__ void cvt_bf16_k(const float* __restrict__ in, __bf16* __restrict__ out, int n8) {
    int i = blockIdx.x * 256 + threadIdx.x;
    if (i >= n8) return;
    const f32x4* p = (const f32x4*)in + (long long)i * 2;
    f32x4 v0 = p[0], v1 = p[1];
    bf16x8 o;
    o[0] = (__bf16)v0[0]; o[1] = (__bf16)v0[1]; o[2] = (__bf16)v0[2]; o[3] = (__bf16)v0[3];
    o[4] = (__bf16)v1[0]; o[5] = (__bf16)v1[1]; o[6] = (__bf16)v1[2]; o[7] = (__bf16)v1[3];
    ((bf16x8*)out)[i] = o;
}

// ------------- fp32 NT GEMM (dt GEMM; fused softplus; optional bf16 out) ------
template<int SOFTPLUS, int OUT_BF16>
__global__ __launch_bounds__(256) void gemm_nt_k(
    const float* __restrict__ A, const float* __restrict__ B, void* __restrict__ Cv,
    const float* __restrict__ bias,
    int M, int N, int K, int lda, int ldb, int ldc,
    long long sA, long long sB, long long sC)
{
    __shared__ float As[16][68];
    __shared__ float Bs[16][68];
    const int bz = blockIdx.z;
    A += (long long)bz * sA; B += (long long)bz * sB;
    const int m0 = blockIdx.y * 64, n0 = blockIdx.x * 64;
    const int tid = threadIdx.x;
    const int lk = tid & 15, lr = tid >> 4;
    const int tx = tid & 15, ty = tid >> 4;
    float acc[4][4] = {};
    for (int k0 = 0; k0 < K; k0 += 16) {
        #pragma unroll
        for (int q = 0; q < 4; ++q) {
            int i = lr + q * 16;
            As[lk][i] = A[(long long)(m0 + i) * lda + k0 + lk];
            Bs[lk][i] = B[(long long)(n0 + i) * ldb + k0 + lk];
        }
        __syncthreads();
        #pragma unroll
        for (int k = 0; k < 16; ++k) {
            float a[4], b[4];
            #pragma unroll
            for (int j = 0; j < 4; ++j) { a[j] = As[k][ty*4+j]; b[j] = Bs[k][tx*4+j]; }
            #pragma unroll
            for (int i = 0; i < 4; ++i)
                #pragma unroll
                for (int j = 0; j < 4; ++j) acc[i][j] += a[i] * b[j];
        }
        __syncthreads();
    }
    #pragma unroll
    for (int i = 0; i < 4; ++i) {
        const int m = m0 + ty * 4 + i;
        float bi = SOFTPLUS ? bias[m] : 0.f;
        #pragma unroll
        for (int j = 0; j < 4; ++j) {
            float v = acc[i][j];
            if (SOFTPLUS) {
                v += bi;
                v = fmaxf(v, 0.f) + log1pf(expf(-fabsf(v)));
            }
            if (OUT_BF16)
                ((__bf16*)Cv)[(long long)bz * sC + (long long)m * ldc + n0 + tx*4 + j] = (__bf16)v;
            else
                ((float*)Cv)[(long long)bz * sC + (long long)m * ldc + n0 + tx*4 + j] = v;
        }
    }
}

// ---------------- Aneg = -exp(A_log) ----------------
__global__ void aneg_k(const float* __restrict__ A_log, float* __restrict__ Aneg) {
    int i = blockIdx.x * 256 + threadIdx.x;
    if (i < D_INNER * D_STATE) Aneg[i] = -expf(A_log[i]);
}

// ------- depthwise causal conv(4) + bias + SiLU, bf16 dual-layout out ---------
__global__ __launch_bounds__(256) void conv_silu_k(const float* __restrict__ xz,
    const float* __restrict__ cw, const float* __restrict__ cb,
    __bf16* __restrict__ u16, __bf16* __restrict__ ut)
{
    __shared__ float tile[32][33];
    const int b = blockIdx.z;
    const int d0 = blockIdx.y * 32, l0 = blockIdx.x * 32;
    const int lx = threadIdx.x, dy = threadIdx.y;   // (32,8)
    #pragma unroll
    for (int j = 0; j < 4; ++j) {
        int d = d0 + dy + j * 8;
        const float* xi = xz + ((long long)b * 2 * D_INNER + d) * SEQLEN;
        int l = l0 + lx;
        float acc = cb[d];
        #pragma unroll
        for (int k = 0; k < 4; ++k) {
            int t = l + k - 3;
            if (t >= 0) acc += xi[t] * cw[d * 4 + k];
        }
        float v = silu_f(acc);
        u16[((long long)b * D_INNER + d) * SEQLEN + l] = (__bf16)v;
        tile[dy + j * 8][lx] = v;
    }
    __syncthreads();
    #pragma unroll
    for (int j = 0; j < 4; ++j) {
        int l = l0 + dy + j * 8;
        ut[((long long)b * SEQLEN + l) * D_INNER + d0 + lx] = (__bf16)tile[lx][dy + j * 8];
    }
}

// ---------------- reduce XKS x_dbl partials -> xdblp ----------------
__global__ void xdbl_red_k(const float* __restrict__ xpart, float* __restrict__ xdbl) {
    int i = blockIdx.x * 256 + threadIdx.x;
    const f32x4* p = (const f32x4*)xpart;
    f32x4 s = p[i];
    #pragma unroll
    for (int ks = 1; ks < XKS; ++ks) {
        f32x4 v = p[(long long)ks * (BATCH * SEQLEN * XSTR / 4) + i];
        s.x += v.x; s.y += v.y; s.z += v.z; s.w += v.w;
    }
    ((f32x4*)xdbl)[i] = s;
}

// ======== fused chunked selective scan: one block per chain ===================
// 256 threads = 4 waves; wave-local chunks (no barriers in main loops);
// delta/u read as bf16x8 (2 loads / 16 steps); B/C scalar coalesced fp32.
__global__ __launch_bounds__(256) void scan_f_k(const __bf16* __restrict__ delta,
    const __bf16* __restrict__ u, const float* __restrict__ xdbl,
    const float* __restrict__ Aneg, __bf16* __restrict__ y)
{
    __shared__ float combA[NCHUNK][16];
    __shared__ float combS[NCHUNK][16];
    __shared__ float sins[NCHUNK][16];
    __shared__ float lp[NCHUNK][16][17];
    const int tid = threadIdx.x;
    const int lane = tid & 63;
    const int n = lane & 15;
    const int c = (tid >> 6) * 4 + (lane >> 4);   // wave-local chunk id
    const int g = blockIdx.x;                     // chain id = b*D_INNER + d
    const int b = g >> 11, d = g & (D_INNER - 1);
    const float a = Aneg[d * D_STATE + n];
    const long long base = (long long)g * SEQLEN + c * CHUNK;
    const bf16x8* dv = (const bf16x8*)(delta + base);
    const bf16x8* uv = (const bf16x8*)(u + base);
    const float* xb = xdbl + ((long long)b * SEQLEN + c * CHUNK) * XSTR + DT_RANK + n;

    // ---- pass 1: chunk-local scan from 0, accumulate A = prod dA ----
    bf16x8 pd[2], pu[2];
    float pB[16];
    pd[0] = dv[0]; pd[1] = dv[1];
    pu[0] = uv[0]; pu[1] = uv[1];
    #pragma unroll
    for (int i = 0; i < 16; ++i) pB[i] = xb[i * XSTR];

    float s = 0.f, ap = 1.f;
    for (int t0 = 0; t0 < CHUNK; t0 += 16) {
        float cd[16], cu[16], cB[16];
        #pragma unroll
        for (int i = 0; i < 16; ++i) {
            cd[i] = (float)pd[i >> 3][i & 7];
            cu[i] = (float)pu[i >> 3][i & 7];
            cB[i] = pB[i];
        }
        if (t0 + 16 < CHUNK) {
            const int nb = (t0 >> 3) + 2;
            pd[0] = dv[nb]; pd[1] = dv[nb + 1];
            pu[0] = uv[nb]; pu[1] = uv[nb + 1];
            const float* xn = xb + (t0 + 16) * XSTR;
            #pragma unroll
            for (int i = 0; i < 16; ++i) pB[i] = xn[i * XSTR];
        }
        float dA[16], wB[16];
        #pragma unroll
        for (int i = 0; i < 16; ++i) {
            dA[i] = __expf(cd[i] * a);
            wB[i] = cd[i] * cu[i] * cB[i];
        }
        #pragma unroll
        for (int i = 0; i < 16; ++i) {
            s = dA[i] * s + wB[i];
            ap *= dA[i];
        }
    }
    combA[c][n] = ap;
    combS[c][n] = s;
    __syncthreads();

    // ---- combine: 16 threads do the serial 16-chunk prefix ----
    if (tid < 16) {
        float av[NCHUNK], sv[NCHUNK];
        #pragma unroll
        for (int cc = 0; cc < NCHUNK; ++cc) { av[cc] = combA[cc][tid]; sv[cc] = combS[cc][tid]; }
        float carry = 0.f;
        #pragma unroll
        for (int cc = 0; cc < NCHUNK; ++cc) {
            sins[cc][tid] = carry;
            carry = sv[cc] + av[cc] * carry;
        }
    }
    __syncthreads();

    // ---- pass 2: re-scan from sinit, emit y bf16 (no barriers) ----
    __bf16* yl = y + base;
    float pC[16];
    pd[0] = dv[0]; pd[1] = dv[1];
    pu[0] = uv[0]; pu[1] = uv[1];
    #pragma unroll
    for (int i = 0; i < 16; ++i) { pB[i] = xb[i * XSTR]; pC[i] = xb[i * XSTR + D_STATE]; }

    s = sins[c][n];
    for (int t0 = 0; t0 < CHUNK; t0 += 16) {
        float cd[16], cu[16], cB[16], cC[16];
        #pragma unroll
        for (int i = 0; i < 16; ++i) {
            cd[i] = (float)pd[i >> 3][i & 7];
            cu[i] = (float)pu[i >> 3][i & 7];
            cB[i] = pB[i];
            cC[i] = pC[i];
        }
        if (t0 + 16 < CHUNK) {
            const int nb = (t0 >> 3) + 2;
            pd[0] = dv[nb]; pd[1] = dv[nb + 1];
            pu[0] = uv[nb]; pu[1] = uv[nb + 1];
            const float* xn = xb + (t0 + 16) * XSTR;
            #pragma unroll
            for (int i = 0; i < 16; ++i) { pB[i] = xn[i * XSTR]; pC[i] = xn[i * XSTR + D_STATE]; }
        }
        float dA[16], wB[16];
        #pragma unroll
        for (int i = 0; i < 16; ++i) {
            dA[i] = __expf(cd[i] * a);
            wB[i] = cd[i] * cu[i] * cB[i];
        }
        #pragma unroll
        for (int i = 0; i < 16; ++i) {
            s = dA[i] * s + wB[i];
            lp[c][n][i] = s * cC[i];
        }
        // same-wave transpose-reduce (lgkmcnt-ordered, no barrier)
        float v[16];
        #pragma unroll
        for (int j = 0; j < 16; ++j) v[j] = lp[c][j][n];
        float acc = 0.f;
        #pragma unroll
        for (int j = 0; j < 16; ++j) acc += v[j];
        yl[t0 + n] = (__bf16)acc;
    }
}

// ---------------- S[b,l] = sum_d Dp[d]*u[b,d,l] ----------------
__global__ void ssum_k(const __bf16* __restrict__ u, const float* __restrict__ Dp,
                       float* __restrict__ S)
{
    int li = blockIdx.x * 256 + threadIdx.x;
    int c = blockIdx.y;
    int b = li >> 11, l = li & (SEQLEN - 1);
    const __bf16* up = u + (long long)b * D_INNER * SEQLEN + l;
    float acc = 0.f;
    for (int d = c * 256; d < c * 256 + 256; ++d)
        acc += Dp[d] * (float)up[(long long)d * SEQLEN];
    atomicAdd(&S[li], acc);
}

// ---------------- y=(y+Dp*u)*silu(z), transposed into ycat16[...,:2048] -------
__global__ __launch_bounds__(256) void ytrans_k(const __bf16* __restrict__ ysc,
    const __bf16* __restrict__ u, const float* __restrict__ xz,
    const float* __restrict__ Dp, __bf16* __restrict__ ycat)
{
    __shared__ float tile[32][33];
    const int b = blockIdx.z;
    const int d0 = blockIdx.y * 32, l0 = blockIdx.x * 32;
    const int lx = threadIdx.x, dy = threadIdx.y;
    #pragma unroll
    for (int j = 0; j < 4; ++j) {
        int d = d0 + dy + j * 8;
        long long i  = ((long long)b * D_INNER + d) * SEQLEN + l0 + lx;
        long long iz = ((long long)b * 2 * D_INNER + D_INNER + d) * SEQLEN + l0 + lx;
        tile[dy + j * 8][lx] = ((float)ysc[i] + Dp[d] * (float)u[i]) * silu_f(xz[iz]);
    }
    __syncthreads();
    #pragma unroll
    for (int j = 0; j < 4; ++j) {
        int l = l0 + dy + j * 8;
        ycat[((long long)b * SEQLEN + l) * (2 * D_INNER) + d0 + lx] = (__bf16)tile[lx][dy + j * 8];
    }
}

// ---------------- y_t -> ycat16[...,2048:] ----------------
__global__ __launch_bounds__(256) void yt_k(const float* __restrict__ xdbl,
    const float* __restrict__ Aneg, const float* __restrict__ S, __bf16* __restrict__ ycat)
{
    __shared__ float Cs[16][33];
    __shared__ float An[16][64];
    __shared__ float Sv[32];
    const int b = blockIdx.z;
    const int d0 = blockIdx.y * 64, l0 = blockIdx.x * 32;
    const int tid = threadIdx.x;
    for (int f = tid; f < 512; f += 256) {
        int n = f & 15, l = f >> 4;
        Cs[n][l] = xdbl[((long long)b * SEQLEN + l0 + l) * XSTR + DT_RANK + D_STATE + n];
    }
    for (int f = tid; f < 1024; f += 256) {
        int n = f & 15, d = f >> 4;
        An[n][d] = Aneg[(d0 + d) * D_STATE + n];
    }
    if (tid < 32) Sv[tid] = S[b * SEQLEN + l0 + tid];
    __syncthreads();
    const int dx = tid & 63, lg = tid >> 6;
    #pragma unroll
    for (int j = 0; j < 8; ++j) {
        int l = lg * 8 + j;
        float acc = Sv[l];
        #pragma unroll
        for (int n = 0; n < 16; ++n) acc += Cs[n][l] * An[n][dx];
        ycat[((long long)b * SEQLEN + l0 + l) * (2 * D_INNER) + D_INNER + d0 + dx] = (__bf16)acc;
    }
}

extern "C" void kernel_launch(void* const* d_in, const int* in_sizes, int n_in,
                              void* d_out, int out_size, void* d_ws, size_t ws_size,
                              hipStream_t stream)
{
    const float* x      = (const float*)d_in[0];
    const float* W_in   = (const float*)d_in[1];
    const float* conv_w = (const float*)d_in[2];
    const float* conv_b = (const float*)d_in[3];
    const float* W_x    = (const float*)d_in[4];
    const float* W_dt   = (const float*)d_in[5];
    const float* b_dt   = (const float*)d_in[6];
    const float* A_log  = (const float*)d_in[7];
    const float* Dp     = (const float*)d_in[8];
    const float* W_out1 = (const float*)d_in[9];
    const float* W_out2 = (const float*)d_in[10];
    float* out = (float*)d_out;
    float* ws  = (float*)d_ws;

    // fp32 region
    float* xz    = ws;                    // 16777216
    float* xdblp = xz    + 16777216;      //   524288 (B*L x 128 padded)
    float* Aneg  = xdblp + 524288;        //    32768
    float* S     = Aneg  + 32768;         //     4096
    float* xpart = S     + 4096;          //  4194304 (8 x 524288)
    // bf16 buffers
    __bf16* u16    = (__bf16*)(xpart + 4194304);   //  8388608 el [b,d,l]
    __bf16* dtb16  = u16    + 8388608;             //  8388608 el (delta)
    __bf16* ysc16  = dtb16  + 8388608;             //  8388608 el
    __bf16* ycat16 = ysc16  + 8388608;             // 16777216 el
    __bf16* h16    = ycat16 + 16777216;            //  8388608 el
    __bf16* Wout116= h16    + 8388608;             //  8388608 el
    __bf16* Wout216= Wout116+ 8388608;             //  2097152 el
    // overlays (regions dead at time of use)
    __bf16* W_in16 = u16;                          // 4194304 el (before conv writes u16)
    __bf16* xb16   = W_in16 + 4194304;             // 4194304 el
    __bf16* ut16   = ycat16;                       // 8388608 el (before ytrans/yt)
    __bf16* Wx16p  = h16;                          // 262144 el (before out1 writes h16)

    hipMemsetAsync(S, 0, 4096 * sizeof(float), stream);
    aneg_k<<<128, 256, 0, stream>>>(A_log, Aneg);

    // bf16 conversions for input GEMM
    cvt_bf16_k<<<2048, 256, 0, stream>>>(W_in, W_in16, 524288);
    cvt_bf16_k<<<2048, 256, 0, stream>>>(x, xb16, 524288);
    // W_x -> bf16 (96 rows), zero-pad rows 96..127
    cvt_bf16_k<<<96, 256, 0, stream>>>(W_x, Wx16p, 24576);
    hipMemsetAsync(Wx16p + 96 * D_INNER, 0, 32 * D_INNER * sizeof(__bf16), stream);

    // xz[b,e,l] = sum_d W_in[e,d] * x[b,l,d]   (M=4096, N=2048, K=1024)
    gemm_bf16_k<0, 0><<<dim3(16, 32, BATCH), 256, 0, stream>>>(
        W_in16, xb16, xz, D_MODEL, D_MODEL, D_MODEL, SEQLEN,
        0LL, (long long)SEQLEN * D_MODEL, (long long)4096 * SEQLEN);

    conv_silu_k<<<dim3(SEQLEN / 32, D_INNER / 32, BATCH), dim3(32, 8), 0, stream>>>(
        xz, conv_w, conv_b, u16, ut16);

    // x_dbl partials: K-split=8 (z selects k-range via sA/sB), 256 blocks
    gemm_bf16_k<0, 0><<<dim3(1, 32, XKS), 256, 0, stream>>>(
        ut16, Wx16p, xpart, D_INNER / XKS, D_INNER, D_INNER, XSTR,
        (long long)(D_INNER / XKS), (long long)(D_INNER / XKS),
        (long long)BATCH * SEQLEN * XSTR);
    xdbl_red_k<<<(BATCH * SEQLEN * XSTR / 4) / 256, 256, 0, stream>>>(xpart, xdblp);

    // dt = softplus(x_dbl @ W_dt^T + b_dt) -> bf16   (fused epilogue)
    gemm_nt_k<1, 1><<<dim3(SEQLEN / 64, D_INNER / 64, BATCH), 256, 0, stream>>>(
        W_dt, xdblp, dtb16, b_dt, D_INNER, SEQLEN, DT_RANK, DT_RANK, XSTR, SEQLEN,
        0LL, (long long)SEQLEN * XSTR, (long long)D_INNER * SEQLEN);

    // fused chunked scan: one block per chain, bf16 in/out
    scan_f_k<<<BATCH * D_INNER, 256, 0, stream>>>(dtb16, u16, xdblp, Aneg, ysc16);

    // weight conversions for output GEMMs
    cvt_bf16_k<<<4096, 256, 0, stream>>>(W_out1, Wout116, 1048576);
    cvt_bf16_k<<<1024, 256, 0, stream>>>(W_out2, Wout216, 262144);

    ssum_k<<<dim3((BATCH * SEQLEN) / 256, 8), 256, 0, stream>>>(u16, Dp, S);

    ytrans_k<<<dim3(SEQLEN / 32, D_INNER / 32, BATCH), dim3(32, 8), 0, stream>>>(ysc16, u16, xz, Dp, ycat16);

    yt_k<<<dim3(SEQLEN / 32, D_INNER / 64, BATCH), 256, 0, stream>>>(xdblp, Aneg, S, ycat16);

    // h = relu(ycat @ W_out1^T) -> bf16   (M=4096, N=2048, K=4096)
    gemm_bf16_k<1, 1><<<dim3(16, 32, 1), 256, 0, stream>>>(
        ycat16, Wout116, h16, 2 * D_INNER, 2 * D_INNER, 2 * D_INNER, D_INNER,
        0LL, 0LL, 0LL);

    // out = h @ W_out2^T   (M=4096, N=1024, K=2048)
    gemm_bf16_k<0, 0><<<dim3(8, 32, 1), 256, 0, stream>>>(
        h16, Wout216, out, D_INNER, D_INNER, D_INNER, D_MODEL,
        0LL, 0LL, 0LL);
}

// Round 22
// 472.041 us; speedup vs baseline: 1.3141x; 1.0331x over previous
//
#include <hip/hip_runtime.h>
#include <hip/hip_bf16.h>
#include <math.h>

#define D_MODEL 1024
#define D_STATE 16
#define D_INNER 2048
#define DT_RANK 64
#define BATCH   2
#define SEQLEN  2048
#define NPROJ   96   // DT_RANK + 2*D_STATE (logical)
#define XSTR    128  // padded x_dbl row stride
#define NCHUNK  16
#define CHUNK   128  // SEQLEN / NCHUNK
#define XKS     8    // x_dbl GEMM K-split

typedef __attribute__((ext_vector_type(8))) __bf16 bf16x8;
typedef __attribute__((ext_vector_type(4))) float f32x4;

__device__ __forceinline__ float silu_f(float x) { return x / (1.f + __expf(-x)); }

__device__ __forceinline__ void gload_lds16(const void* g, void* l) {
    __builtin_amdgcn_global_load_lds((const __attribute__((address_space(1))) void*)g,
                                     (__attribute__((address_space(3))) void*)l, 16, 0, 0);
}

// ---------------- bf16 MFMA NT GEMM: C[m,n] = sum_k A[m,k]*B[n,k] -------------
// 128x128 tile, BK=32, 4 waves. Bijective XCD swizzle on (y,x) flat id.
template<int RELU, int OUT_BF16>
__global__ __launch_bounds__(256) void gemm_bf16_k(
    const __bf16* __restrict__ A, const __bf16* __restrict__ B, void* __restrict__ Cv,
    int K, int lda, int ldb, int ldc, long long sA, long long sB, long long sC)
{
    __shared__ alignas(16) __bf16 As[128 * 32];
    __shared__ alignas(16) __bf16 Bs[128 * 32];
    const int bz = blockIdx.z;
    A += (long long)bz * sA;
    B += (long long)bz * sB;
    int nwg = gridDim.x * gridDim.y;
    int flat = blockIdx.y * gridDim.x + blockIdx.x;
    int swz = (nwg & 7) ? flat : ((flat & 7) * (nwg >> 3) + (flat >> 3));
    const int m0 = (swz / gridDim.x) * 128, n0 = (swz % gridDim.x) * 128;
    const int tid = threadIdx.x;
    const int lane = tid & 63;
    const int wv = tid >> 6;
    const int wr = wv >> 1, wc = wv & 1;

    f32x4 acc[4][4];
    #pragma unroll
    for (int i = 0; i < 4; ++i)
        #pragma unroll
        for (int j = 0; j < 4; ++j) acc[i][j] = (f32x4){0.f, 0.f, 0.f, 0.f};

    const int ko = (lane >> 4) * 8;
    const int fr = lane & 15;

    for (int k0 = 0; k0 < K; k0 += 32) {
        #pragma unroll
        for (int q = 0; q < 2; ++q) {
            int f = tid + q * 256;
            int row = f >> 2, c16 = f & 3;
            gload_lds16(A + (long long)(m0 + row) * lda + k0 + c16 * 8, As + f * 8);
            gload_lds16(B + (long long)(n0 + row) * ldb + k0 + c16 * 8, Bs + f * 8);
        }
        __syncthreads();
        bf16x8 a[4], b[4];
        #pragma unroll
        for (int i = 0; i < 4; ++i) {
            a[i] = *(const bf16x8*)(As + (wr * 64 + i * 16 + fr) * 32 + ko);
            b[i] = *(const bf16x8*)(Bs + (wc * 64 + i * 16 + fr) * 32 + ko);
        }
        #pragma unroll
        for (int i = 0; i < 4; ++i)
            #pragma unroll
            for (int j = 0; j < 4; ++j)
                acc[i][j] = __builtin_amdgcn_mfma_f32_16x16x32_bf16(a[i], b[j], acc[i][j], 0, 0, 0);
        __syncthreads();
    }

    #pragma unroll
    for (int i = 0; i < 4; ++i) {
        const int row = m0 + wr * 64 + i * 16 + (lane >> 4) * 4;
        #pragma unroll
        for (int j = 0; j < 4; ++j) {
            const int col = n0 + wc * 64 + j * 16 + fr;
            #pragma unroll
            for (int r = 0; r < 4; ++r) {
                float v = acc[i][j][r];
                if (RELU) v = fmaxf(v, 0.f);
                if (OUT_BF16)
                    ((__bf16*)Cv)[(long long)bz * sC + (long long)(row + r) * ldc + col] = (__bf16)v;
                else
                    ((float*)Cv)[(long long)bz * sC + (long long)(row + r) * ldc + col] = v;
            }
        }
    }
}

// ---------------- f32 -> bf16 pack (8 per thread) ----------------
__global__ void cvt_bf16_k(const float* __restrict__ in, __bf16* __restrict__ out, int n8) {
    int i = blockIdx.x * 256 + threadIdx.x;
    if (i >= n8) return;
    const f32x4* p = (const f32x4*)in + (long long)i * 2;
    f32x4 v0 = p[0], v1 = p[1];
    bf16x8 o;
    o[0] = (__bf16)v0[0]; o[1] = (__bf16)v0[1]; o[2] = (__bf16)v0[2]; o[3] = (__bf16)v0[3];
    o[4] = (__bf16)v1[0]; o[5] = (__bf16)v1[1]; o[6] = (__bf16)v1[2]; o[7] = (__bf16)v1[3];
    ((bf16x8*)out)[i] = o;
}

// ------------- fp32 NT GEMM (dt GEMM; fused softplus; optional bf16 out) ------
template<int SOFTPLUS, int OUT_BF16>
__global__ __launch_bounds__(256) void gemm_nt_k(
    const float* __restrict__ A, const float* __restrict__ B, void* __restrict__ Cv,
    const float* __restrict__ bias,
    int M, int N, int K, int lda, int ldb, int ldc,
    long long sA, long long sB, long long sC)
{
    __shared__ float As[16][68];
    __shared__ float Bs[16][68];
    const int bz = blockIdx.z;
    A += (long long)bz * sA; B += (long long)bz * sB;
    const int m0 = blockIdx.y * 64, n0 = blockIdx.x * 64;
    const int tid = threadIdx.x;
    const int lk = tid & 15, lr = tid >> 4;
    const int tx = tid & 15, ty = tid >> 4;
    float acc[4][4] = {};
    for (int k0 = 0; k0 < K; k0 += 16) {
        #pragma unroll
        for (int q = 0; q < 4; ++q) {
            int i = lr + q * 16;
            As[lk][i] = A[(long long)(m0 + i) * lda + k0 + lk];
            Bs[lk][i] = B[(long long)(n0 + i) * ldb + k0 + lk];
        }
        __syncthreads();
        #pragma unroll
        for (int k = 0; k < 16; ++k) {
            float a[4], b[4];
            #pragma unroll
            for (int j = 0; j < 4; ++j) { a[j] = As[k][ty*4+j]; b[j] = Bs[k][tx*4+j]; }
            #pragma unroll
            for (int i = 0; i < 4; ++i)
                #pragma unroll
                for (int j = 0; j < 4; ++j) acc[i][j] += a[i] * b[j];
        }
        __syncthreads();
    }
    #pragma unroll
    for (int i = 0; i < 4; ++i) {
        const int m = m0 + ty * 4 + i;
        float bi = SOFTPLUS ? bias[m] : 0.f;
        #pragma unroll
        for (int j = 0; j < 4; ++j) {
            float v = acc[i][j];
            if (SOFTPLUS) {
                v += bi;
                v = fmaxf(v, 0.f) + log1pf(expf(-fabsf(v)));
            }
            if (OUT_BF16)
                ((__bf16*)Cv)[(long long)bz * sC + (long long)m * ldc + n0 + tx*4 + j] = (__bf16)v;
            else
                ((float*)Cv)[(long long)bz * sC + (long long)m * ldc + n0 + tx*4 + j] = v;
        }
    }
}

// ---------------- Aneg = -exp(A_log) ----------------
__global__ void aneg_k(const float* __restrict__ A_log, float* __restrict__ Aneg) {
    int i = blockIdx.x * 256 + threadIdx.x;
    if (i < D_INNER * D_STATE) Aneg[i] = -expf(A_log[i]);
}

// ------- depthwise causal conv(4) + bias + SiLU; bf16 in, bf16 dual out -------
__global__ __launch_bounds__(256) void conv_silu_k(const __bf16* __restrict__ xz,
    const float* __restrict__ cw, const float* __restrict__ cb,
    __bf16* __restrict__ u16, __bf16* __restrict__ ut)
{
    __shared__ float tile[32][33];
    const int b = blockIdx.z;
    const int d0 = blockIdx.y * 32, l0 = blockIdx.x * 32;
    const int lx = threadIdx.x, dy = threadIdx.y;   // (32,8)
    #pragma unroll
    for (int j = 0; j < 4; ++j) {
        int d = d0 + dy + j * 8;
        const __bf16* xi = xz + ((long long)b * 2 * D_INNER + d) * SEQLEN;
        int l = l0 + lx;
        float acc = cb[d];
        #pragma unroll
        for (int k = 0; k < 4; ++k) {
            int t = l + k - 3;
            if (t >= 0) acc += (float)xi[t] * cw[d * 4 + k];
        }
        float v = silu_f(acc);
        u16[((long long)b * D_INNER + d) * SEQLEN + l] = (__bf16)v;
        tile[dy + j * 8][lx] = v;
    }
    __syncthreads();
    #pragma unroll
    for (int j = 0; j < 4; ++j) {
        int l = l0 + dy + j * 8;
        ut[((long long)b * SEQLEN + l) * D_INNER + d0 + lx] = (__bf16)tile[lx][dy + j * 8];
    }
}

// ---------------- reduce XKS x_dbl partials -> xdblp ----------------
__global__ void xdbl_red_k(const float* __restrict__ xpart, float* __restrict__ xdbl) {
    int i = blockIdx.x * 256 + threadIdx.x;
    const f32x4* p = (const f32x4*)xpart;
    f32x4 s = p[i];
    #pragma unroll
    for (int ks = 1; ks < XKS; ++ks) {
        f32x4 v = p[(long long)ks * (BATCH * SEQLEN * XSTR / 4) + i];
        s.x += v.x; s.y += v.y; s.z += v.z; s.w += v.w;
    }
    ((f32x4*)xdbl)[i] = s;
}

// ======== fused chunked selective scan: one block per chain ===================
// 256 threads = 4 waves; wave-local chunks (no barriers in main loops);
// delta/u read as bf16x8 (2 loads / 16 steps); B/C scalar coalesced fp32.
__global__ __launch_bounds__(256) void scan_f_k(const __bf16* __restrict__ delta,
    const __bf16* __restrict__ u, const float* __restrict__ xdbl,
    const float* __restrict__ Aneg, __bf16* __restrict__ y)
{
    __shared__ float combA[NCHUNK][16];
    __shared__ float combS[NCHUNK][16];
    __shared__ float sins[NCHUNK][16];
    __shared__ float lp[NCHUNK][16][17];
    const int tid = threadIdx.x;
    const int lane = tid & 63;
    const int n = lane & 15;
    const int c = (tid >> 6) * 4 + (lane >> 4);   // wave-local chunk id
    const int g = blockIdx.x;                     // chain id = b*D_INNER + d
    const int b = g >> 11, d = g & (D_INNER - 1);
    const float a = Aneg[d * D_STATE + n];
    const long long base = (long long)g * SEQLEN + c * CHUNK;
    const bf16x8* dv = (const bf16x8*)(delta + base);
    const bf16x8* uv = (const bf16x8*)(u + base);
    const float* xb = xdbl + ((long long)b * SEQLEN + c * CHUNK) * XSTR + DT_RANK + n;

    // ---- pass 1: chunk-local scan from 0, accumulate A = prod dA ----
    bf16x8 pd[2], pu[2];
    float pB[16];
    pd[0] = dv[0]; pd[1] = dv[1];
    pu[0] = uv[0]; pu[1] = uv[1];
    #pragma unroll
    for (int i = 0; i < 16; ++i) pB[i] = xb[i * XSTR];

    float s = 0.f, ap = 1.f;
    for (int t0 = 0; t0 < CHUNK; t0 += 16) {
        float cd[16], cu[16], cB[16];
        #pragma unroll
        for (int i = 0; i < 16; ++i) {
            cd[i] = (float)pd[i >> 3][i & 7];
            cu[i] = (float)pu[i >> 3][i & 7];
            cB[i] = pB[i];
        }
        if (t0 + 16 < CHUNK) {
            const int nb = (t0 >> 3) + 2;
            pd[0] = dv[nb]; pd[1] = dv[nb + 1];
            pu[0] = uv[nb]; pu[1] = uv[nb + 1];
            const float* xn = xb + (t0 + 16) * XSTR;
            #pragma unroll
            for (int i = 0; i < 16; ++i) pB[i] = xn[i * XSTR];
        }
        float dA[16], wB[16];
        #pragma unroll
        for (int i = 0; i < 16; ++i) {
            dA[i] = __expf(cd[i] * a);
            wB[i] = cd[i] * cu[i] * cB[i];
        }
        #pragma unroll
        for (int i = 0; i < 16; ++i) {
            s = dA[i] * s + wB[i];
            ap *= dA[i];
        }
    }
    combA[c][n] = ap;
    combS[c][n] = s;
    __syncthreads();

    // ---- combine: 16 threads do the serial 16-chunk prefix ----
    if (tid < 16) {
        float av[NCHUNK], sv[NCHUNK];
        #pragma unroll
        for (int cc = 0; cc < NCHUNK; ++cc) { av[cc] = combA[cc][tid]; sv[cc] = combS[cc][tid]; }
        float carry = 0.f;
        #pragma unroll
        for (int cc = 0; cc < NCHUNK; ++cc) {
            sins[cc][tid] = carry;
            carry = sv[cc] + av[cc] * carry;
        }
    }
    __syncthreads();

    // ---- pass 2: re-scan from sinit, emit y bf16 (no barriers) ----
    __bf16* yl = y + base;
    float pC[16];
    pd[0] = dv[0]; pd[1] = dv[1];
    pu[0] = uv[0]; pu[1] = uv[1];
    #pragma unroll
    for (int i = 0; i < 16; ++i) { pB[i] = xb[i * XSTR]; pC[i] = xb[i * XSTR + D_STATE]; }

    s = sins[c][n];
    for (int t0 = 0; t0 < CHUNK; t0 += 16) {
        float cd[16], cu[16], cB[16], cC[16];
        #pragma unroll
        for (int i = 0; i < 16; ++i) {
            cd[i] = (float)pd[i >> 3][i & 7];
            cu[i] = (float)pu[i >> 3][i & 7];
            cB[i] = pB[i];
            cC[i] = pC[i];
        }
        if (t0 + 16 < CHUNK) {
            const int nb = (t0 >> 3) + 2;
            pd[0] = dv[nb]; pd[1] = dv[nb + 1];
            pu[0] = uv[nb]; pu[1] = uv[nb + 1];
            const float* xn = xb + (t0 + 16) * XSTR;
            #pragma unroll
            for (int i = 0; i < 16; ++i) { pB[i] = xn[i * XSTR]; pC[i] = xn[i * XSTR + D_STATE]; }
        }
        float dA[16], wB[16];
        #pragma unroll
        for (int i = 0; i < 16; ++i) {
            dA[i] = __expf(cd[i] * a);
            wB[i] = cd[i] * cu[i] * cB[i];
        }
        #pragma unroll
        for (int i = 0; i < 16; ++i) {
            s = dA[i] * s + wB[i];
            lp[c][n][i] = s * cC[i];
        }
        // same-wave transpose-reduce (lgkmcnt-ordered, no barrier)
        float v[16];
        #pragma unroll
        for (int j = 0; j < 16; ++j) v[j] = lp[c][j][n];
        float acc = 0.f;
        #pragma unroll
        for (int j = 0; j < 16; ++j) acc += v[j];
        yl[t0 + n] = (__bf16)acc;
    }
}

// ------- S[b,l] = sum_d Dp[d]*u[b,l,d] from d-contiguous ut16 (no atomics) ----
// 512 blocks x 256 threads; block handles 8 l's, 32 d-groups of 64.
__global__ __launch_bounds__(256) void ssum_k(const __bf16* __restrict__ ut,
    const float* __restrict__ Dp, float* __restrict__ S)
{
    __shared__ float part[8][33];
    const int tid = threadIdx.x;
    const int ls = tid >> 5;       // 0..7
    const int dg = tid & 31;       // 0..31
    const int li = blockIdx.x * 8 + ls;
    const bf16x8* row = (const bf16x8*)(ut + (long long)li * D_INNER) + dg * 8;
    float acc = 0.f;
    #pragma unroll
    for (int q = 0; q < 8; ++q) {
        bf16x8 v = row[q];
        #pragma unroll
        for (int j = 0; j < 8; ++j) acc += Dp[dg * 64 + q * 8 + j] * (float)v[j];
    }
    part[ls][dg] = acc;
    __syncthreads();
    if (tid < 8) {
        float s = 0.f;
        #pragma unroll
        for (int q = 0; q < 32; ++q) s += part[tid][q];
        S[blockIdx.x * 8 + tid] = s;
    }
}

// ---------------- y=(y+Dp*u)*silu(z), transposed into ycat16[...,:2048] -------
__global__ __launch_bounds__(256) void ytrans_k(const __bf16* __restrict__ ysc,
    const __bf16* __restrict__ u, const __bf16* __restrict__ xz,
    const float* __restrict__ Dp, __bf16* __restrict__ ycat)
{
    __shared__ float tile[32][33];
    const int b = blockIdx.z;
    const int d0 = blockIdx.y * 32, l0 = blockIdx.x * 32;
    const int lx = threadIdx.x, dy = threadIdx.y;
    #pragma unroll
    for (int j = 0; j < 4; ++j) {
        int d = d0 + dy + j * 8;
        long long i  = ((long long)b * D_INNER + d) * SEQLEN + l0 + lx;
        long long iz = ((long long)b * 2 * D_INNER + D_INNER + d) * SEQLEN + l0 + lx;
        tile[dy + j * 8][lx] = ((float)ysc[i] + Dp[d] * (float)u[i]) * silu_f((float)xz[iz]);
    }
    __syncthreads();
    #pragma unroll
    for (int j = 0; j < 4; ++j) {
        int l = l0 + dy + j * 8;
        ycat[((long long)b * SEQLEN + l) * (2 * D_INNER) + d0 + lx] = (__bf16)tile[lx][dy + j * 8];
    }
}

// ---------------- y_t -> ycat16[...,2048:] ----------------
__global__ __launch_bounds__(256) void yt_k(const float* __restrict__ xdbl,
    const float* __restrict__ Aneg, const float* __restrict__ S, __bf16* __restrict__ ycat)
{
    __shared__ float Cs[16][33];
    __shared__ float An[16][64];
    __shared__ float Sv[32];
    const int b = blockIdx.z;
    const int d0 = blockIdx.y * 64, l0 = blockIdx.x * 32;
    const int tid = threadIdx.x;
    for (int f = tid; f < 512; f += 256) {
        int n = f & 15, l = f >> 4;
        Cs[n][l] = xdbl[((long long)b * SEQLEN + l0 + l) * XSTR + DT_RANK + D_STATE + n];
    }
    for (int f = tid; f < 1024; f += 256) {
        int n = f & 15, d = f >> 4;
        An[n][d] = Aneg[(d0 + d) * D_STATE + n];
    }
    if (tid < 32) Sv[tid] = S[b * SEQLEN + l0 + tid];
    __syncthreads();
    const int dx = tid & 63, lg = tid >> 6;
    #pragma unroll
    for (int j = 0; j < 8; ++j) {
        int l = lg * 8 + j;
        float acc = Sv[l];
        #pragma unroll
        for (int n = 0; n < 16; ++n) acc += Cs[n][l] * An[n][dx];
        ycat[((long long)b * SEQLEN + l0 + l) * (2 * D_INNER) + D_INNER + d0 + dx] = (__bf16)acc;
    }
}

extern "C" void kernel_launch(void* const* d_in, const int* in_sizes, int n_in,
                              void* d_out, int out_size, void* d_ws, size_t ws_size,
                              hipStream_t stream)
{
    const float* x      = (const float*)d_in[0];
    const float* W_in   = (const float*)d_in[1];
    const float* conv_w = (const float*)d_in[2];
    const float* conv_b = (const float*)d_in[3];
    const float* W_x    = (const float*)d_in[4];
    const float* W_dt   = (const float*)d_in[5];
    const float* b_dt   = (const float*)d_in[6];
    const float* A_log  = (const float*)d_in[7];
    const float* Dp     = (const float*)d_in[8];
    const float* W_out1 = (const float*)d_in[9];
    const float* W_out2 = (const float*)d_in[10];
    float* out = (float*)d_out;
    float* ws  = (float*)d_ws;

    // layout (floats unless noted)
    __bf16* xz16 = (__bf16*)ws;                    // 16777216 el (8388608 f)
    float* xdblp = ws + 8388608;                   //   524288 (B*L x 128)
    float* Aneg  = xdblp + 524288;                 //    32768
    float* S     = Aneg + 32768;                   //     4096
    float* xpart = S + 4096;                       //  4194304 (8 x 524288)
    __bf16* u16    = (__bf16*)(xpart + 4194304);   //  8388608 el [b,d,l]
    __bf16* dtb16  = u16    + 8388608;             //  8388608 el (delta)
    __bf16* ysc16  = dtb16  + 8388608;             //  8388608 el
    __bf16* ycat16 = ysc16  + 8388608;             // 16777216 el
    __bf16* h16    = ycat16 + 16777216;            //  8388608 el
    __bf16* Wout116= h16    + 8388608;             //  8388608 el
    __bf16* Wout216= Wout116+ 8388608;             //  2097152 el
    // overlays (regions dead at time of use)
    __bf16* W_in16 = u16;                          // before conv writes u16
    __bf16* xb16   = W_in16 + 4194304;
    __bf16* ut16   = ycat16;                       // before ytrans/yt write ycat
    __bf16* Wx16p  = h16;                          // before out1 writes h16

    aneg_k<<<128, 256, 0, stream>>>(A_log, Aneg);

    // bf16 conversions for input GEMM
    cvt_bf16_k<<<2048, 256, 0, stream>>>(W_in, W_in16, 524288);
    cvt_bf16_k<<<2048, 256, 0, stream>>>(x, xb16, 524288);
    // W_x -> bf16 (96 rows), zero-pad rows 96..127
    cvt_bf16_k<<<96, 256, 0, stream>>>(W_x, Wx16p, 24576);
    hipMemsetAsync(Wx16p + 96 * D_INNER, 0, 32 * D_INNER * sizeof(__bf16), stream);

    // xz[b,e,l] = sum_d W_in[e,d] * x[b,l,d] -> bf16  (M=4096, N=2048, K=1024)
    gemm_bf16_k<0, 1><<<dim3(16, 32, BATCH), 256, 0, stream>>>(
        W_in16, xb16, xz16, D_MODEL, D_MODEL, D_MODEL, SEQLEN,
        0LL, (long long)SEQLEN * D_MODEL, (long long)4096 * SEQLEN);

    conv_silu_k<<<dim3(SEQLEN / 32, D_INNER / 32, BATCH), dim3(32, 8), 0, stream>>>(
        xz16, conv_w, conv_b, u16, ut16);

    // x_dbl partials: K-split=8 (z selects k-range via sA/sB), 256 blocks
    gemm_bf16_k<0, 0><<<dim3(1, 32, XKS), 256, 0, stream>>>(
        ut16, Wx16p, xpart, D_INNER / XKS, D_INNER, D_INNER, XSTR,
        (long long)(D_INNER / XKS), (long long)(D_INNER / XKS),
        (long long)BATCH * SEQLEN * XSTR);
    xdbl_red_k<<<(BATCH * SEQLEN * XSTR / 4) / 256, 256, 0, stream>>>(xpart, xdblp);

    // dt = softplus(x_dbl @ W_dt^T + b_dt) -> bf16   (fused epilogue)
    gemm_nt_k<1, 1><<<dim3(SEQLEN / 64, D_INNER / 64, BATCH), 256, 0, stream>>>(
        W_dt, xdblp, dtb16, b_dt, D_INNER, SEQLEN, DT_RANK, DT_RANK, XSTR, SEQLEN,
        0LL, (long long)SEQLEN * XSTR, (long long)D_INNER * SEQLEN);

    // fused chunked scan: one block per chain, bf16 in/out
    scan_f_k<<<BATCH * D_INNER, 256, 0, stream>>>(dtb16, u16, xdblp, Aneg, ysc16);

    // weight conversions for output GEMMs
    cvt_bf16_k<<<4096, 256, 0, stream>>>(W_out1, Wout116, 1048576);
    cvt_bf16_k<<<1024, 256, 0, stream>>>(W_out2, Wout216, 262144);

    ssum_k<<<(BATCH * SEQLEN) / 8, 256, 0, stream>>>(ut16, Dp, S);

    ytrans_k<<<dim3(SEQLEN / 32, D_INNER / 32, BATCH), dim3(32, 8), 0, stream>>>(ysc16, u16, xz16, Dp, ycat16);

    yt_k<<<dim3(SEQLEN / 32, D_INNER / 64, BATCH), 256, 0, stream>>>(xdblp, Aneg, S, ycat16);

    // h = relu(ycat @ W_out1^T) -> bf16   (M=4096, N=2048, K=4096)
    gemm_bf16_k<1, 1><<<dim3(16, 32, 1), 256, 0, stream>>>(
        ycat16, Wout116, h16, 2 * D_INNER, 2 * D_INNER, 2 * D_INNER, D_INNER,
        0LL, 0LL, 0LL);

    // out = h @ W_out2^T   (M=4096, N=1024, K=2048)
    gemm_bf16_k<0, 0><<<dim3(8, 32, 1), 256, 0, stream>>>(
        h16, Wout216, out, D_INNER, D_INNER, D_INNER, D_MODEL,
        0LL, 0LL, 0LL);
}

// Round 25
// 462.103 us; speedup vs baseline: 1.3424x; 1.0215x over previous
//
#include <hip/hip_runtime.h>
#include <hip/hip_bf16.h>
#include <math.h>

#define D_MODEL 1024
#define D_STATE 16
#define D_INNER 2048
#define DT_RANK 64
#define BATCH   2
#define SEQLEN  2048
#define NPROJ   96   // DT_RANK + 2*D_STATE (logical)
#define XSTR    128  // padded x_dbl row stride
#define NCHUNK  16
#define CHUNK   128  // SEQLEN / NCHUNK
#define XKS     8    // x_dbl GEMM K-split

typedef __attribute__((ext_vector_type(8))) __bf16 bf16x8;
typedef __attribute__((ext_vector_type(4))) float f32x4;

__device__ __forceinline__ float silu_f(float x) { return x / (1.f + __expf(-x)); }

__device__ __forceinline__ void gload_lds16(const void* g, void* l) {
    __builtin_amdgcn_global_load_lds((const __attribute__((address_space(1))) void*)g,
                                     (__attribute__((address_space(3))) void*)l, 16, 0, 0);
}

__device__ __forceinline__ void cvt8(const float* in, __bf16* out, long long i8) {
    const f32x4* p = (const f32x4*)in + i8 * 2;
    f32x4 v0 = p[0], v1 = p[1];
    bf16x8 o;
    o[0] = (__bf16)v0.x; o[1] = (__bf16)v0.y; o[2] = (__bf16)v0.z; o[3] = (__bf16)v0.w;
    o[4] = (__bf16)v1.x; o[5] = (__bf16)v1.y; o[6] = (__bf16)v1.z; o[7] = (__bf16)v1.w;
    ((bf16x8*)out)[i8] = o;
}

// ---------------- bf16 MFMA NT GEMM: C[m,n] = sum_k A[m,k]*B[n,k] -------------
// 128x128 tile, BK=32, 4 waves. Bijective XCD swizzle on (y,x) flat id.
template<int RELU, int OUT_BF16>
__global__ __launch_bounds__(256) void gemm_bf16_k(
    const __bf16* __restrict__ A, const __bf16* __restrict__ B, void* __restrict__ Cv,
    int K, int lda, int ldb, int ldc, long long sA, long long sB, long long sC)
{
    __shared__ alignas(16) __bf16 As[128 * 32];
    __shared__ alignas(16) __bf16 Bs[128 * 32];
    const int bz = blockIdx.z;
    A += (long long)bz * sA;
    B += (long long)bz * sB;
    int nwg = gridDim.x * gridDim.y;
    int flat = blockIdx.y * gridDim.x + blockIdx.x;
    int swz = (nwg & 7) ? flat : ((flat & 7) * (nwg >> 3) + (flat >> 3));
    const int m0 = (swz / gridDim.x) * 128, n0 = (swz % gridDim.x) * 128;
    const int tid = threadIdx.x;
    const int lane = tid & 63;
    const int wv = tid >> 6;
    const int wr = wv >> 1, wc = wv & 1;

    f32x4 acc[4][4];
    #pragma unroll
    for (int i = 0; i < 4; ++i)
        #pragma unroll
        for (int j = 0; j < 4; ++j) acc[i][j] = (f32x4){0.f, 0.f, 0.f, 0.f};

    const int ko = (lane >> 4) * 8;
    const int fr = lane & 15;

    for (int k0 = 0; k0 < K; k0 += 32) {
        #pragma unroll
        for (int q = 0; q < 2; ++q) {
            int f = tid + q * 256;
            int row = f >> 2, c16 = f & 3;
            gload_lds16(A + (long long)(m0 + row) * lda + k0 + c16 * 8, As + f * 8);
            gload_lds16(B + (long long)(n0 + row) * ldb + k0 + c16 * 8, Bs + f * 8);
        }
        __syncthreads();
        bf16x8 a[4], b[4];
        #pragma unroll
        for (int i = 0; i < 4; ++i) {
            a[i] = *(const bf16x8*)(As + (wr * 64 + i * 16 + fr) * 32 + ko);
            b[i] = *(const bf16x8*)(Bs + (wc * 64 + i * 16 + fr) * 32 + ko);
        }
        #pragma unroll
        for (int i = 0; i < 4; ++i)
            #pragma unroll
            for (int j = 0; j < 4; ++j)
                acc[i][j] = __builtin_amdgcn_mfma_f32_16x16x32_bf16(a[i], b[j], acc[i][j], 0, 0, 0);
        __syncthreads();
    }

    #pragma unroll
    for (int i = 0; i < 4; ++i) {
        const int row = m0 + wr * 64 + i * 16 + (lane >> 4) * 4;
        #pragma unroll
        for (int j = 0; j < 4; ++j) {
            const int col = n0 + wc * 64 + j * 16 + fr;
            #pragma unroll
            for (int r = 0; r < 4; ++r) {
                float v = acc[i][j][r];
                if (RELU) v = fmaxf(v, 0.f);
                if (OUT_BF16)
                    ((__bf16*)Cv)[(long long)bz * sC + (long long)(row + r) * ldc + col] = (__bf16)v;
                else
                    ((float*)Cv)[(long long)bz * sC + (long long)(row + r) * ldc + col] = v;
            }
        }
    }
}

// ------ fused front conversions: W_in, x, Wx(+zero pad) -> bf16 ---------------
// g8 ranges: [0,524288) W_in | [524288,1048576) x | [1048576,1073152) Wx | rest pad
__global__ void cvt_front_k(const float* __restrict__ W_in, const float* __restrict__ x,
                            const float* __restrict__ Wx, __bf16* __restrict__ W_in16,
                            __bf16* __restrict__ xb16, __bf16* __restrict__ Wx16p)
{
    long long i = (long long)blockIdx.x * 256 + threadIdx.x;
    if (i < 524288) {
        cvt8(W_in, W_in16, i);
    } else if (i < 1048576) {
        cvt8(x, xb16, i - 524288);
    } else if (i < 1048576 + 24576) {
        cvt8(Wx, Wx16p, i - 1048576);
    } else if (i < 1048576 + 32768) {
        bf16x8 z = {};
        ((bf16x8*)Wx16p)[i - 1048576] = z;
    }
}

// ------ fused back conversions: W_out1, W_out2 -> bf16 ------------------------
__global__ void cvt_back_k(const float* __restrict__ W_out1, const float* __restrict__ W_out2,
                           __bf16* __restrict__ Wout116, __bf16* __restrict__ Wout216)
{
    long long i = (long long)blockIdx.x * 256 + threadIdx.x;
    if (i < 1048576) cvt8(W_out1, Wout116, i);
    else if (i < 1048576 + 262144) cvt8(W_out2, Wout216, i - 1048576);
}

// ------------- fp32 NT GEMM (dt GEMM; fused softplus; optional bf16 out) ------
template<int SOFTPLUS, int OUT_BF16>
__global__ __launch_bounds__(256) void gemm_nt_k(
    const float* __restrict__ A, const float* __restrict__ B, void* __restrict__ Cv,
    const float* __restrict__ bias,
    int M, int N, int K, int lda, int ldb, int ldc,
    long long sA, long long sB, long long sC)
{
    __shared__ float As[16][68];
    __shared__ float Bs[16][68];
    const int bz = blockIdx.z;
    A += (long long)bz * sA; B += (long long)bz * sB;
    const int m0 = blockIdx.y * 64, n0 = blockIdx.x * 64;
    const int tid = threadIdx.x;
    const int lk = tid & 15, lr = tid >> 4;
    const int tx = tid & 15, ty = tid >> 4;
    float acc[4][4] = {};
    for (int k0 = 0; k0 < K; k0 += 16) {
        #pragma unroll
        for (int q = 0; q < 4; ++q) {
            int i = lr + q * 16;
            As[lk][i] = A[(long long)(m0 + i) * lda + k0 + lk];
            Bs[lk][i] = B[(long long)(n0 + i) * ldb + k0 + lk];
        }
        __syncthreads();
        #pragma unroll
        for (int k = 0; k < 16; ++k) {
            float a[4], b[4];
            #pragma unroll
            for (int j = 0; j < 4; ++j) { a[j] = As[k][ty*4+j]; b[j] = Bs[k][tx*4+j]; }
            #pragma unroll
            for (int i = 0; i < 4; ++i)
                #pragma unroll
                for (int j = 0; j < 4; ++j) acc[i][j] += a[i] * b[j];
        }
        __syncthreads();
    }
    #pragma unroll
    for (int i = 0; i < 4; ++i) {
        const int m = m0 + ty * 4 + i;
        float bi = SOFTPLUS ? bias[m] : 0.f;
        #pragma unroll
        for (int j = 0; j < 4; ++j) {
            float v = acc[i][j];
            if (SOFTPLUS) {
                v += bi;
                v = fmaxf(v, 0.f) + log1pf(expf(-fabsf(v)));
            }
            if (OUT_BF16)
                ((__bf16*)Cv)[(long long)bz * sC + (long long)m * ldc + n0 + tx*4 + j] = (__bf16)v;
            else
                ((float*)Cv)[(long long)bz * sC + (long long)m * ldc + n0 + tx*4 + j] = v;
        }
    }
}

// ------- depthwise causal conv(4) + bias + SiLU; bf16 in, bf16 dual out -------
__global__ __launch_bounds__(256) void conv_silu_k(const __bf16* __restrict__ xz,
    const float* __restrict__ cw, const float* __restrict__ cb,
    __bf16* __restrict__ u16, __bf16* __restrict__ ut)
{
    __shared__ float tile[32][33];
    const int b = blockIdx.z;
    const int d0 = blockIdx.y * 32, l0 = blockIdx.x * 32;
    const int lx = threadIdx.x, dy = threadIdx.y;   // (32,8)
    #pragma unroll
    for (int j = 0; j < 4; ++j) {
        int d = d0 + dy + j * 8;
        const __bf16* xi = xz + ((long long)b * 2 * D_INNER + d) * SEQLEN;
        int l = l0 + lx;
        float acc = cb[d];
        #pragma unroll
        for (int k = 0; k < 4; ++k) {
            int t = l + k - 3;
            if (t >= 0) acc += (float)xi[t] * cw[d * 4 + k];
        }
        float v = silu_f(acc);
        u16[((long long)b * D_INNER + d) * SEQLEN + l] = (__bf16)v;
        tile[dy + j * 8][lx] = v;
    }
    __syncthreads();
    #pragma unroll
    for (int j = 0; j < 4; ++j) {
        int l = l0 + dy + j * 8;
        ut[((long long)b * SEQLEN + l) * D_INNER + d0 + lx] = (__bf16)tile[lx][dy + j * 8];
    }
}

// ---------------- reduce XKS x_dbl partials -> xdblp ----------------
__global__ void xdbl_red_k(const float* __restrict__ xpart, float* __restrict__ xdbl) {
    int i = blockIdx.x * 256 + threadIdx.x;
    const f32x4* p = (const f32x4*)xpart;
    f32x4 s = p[i];
    #pragma unroll
    for (int ks = 1; ks < XKS; ++ks) {
        f32x4 v = p[(long long)ks * (BATCH * SEQLEN * XSTR / 4) + i];
        s.x += v.x; s.y += v.y; s.z += v.z; s.w += v.w;
    }
    ((f32x4*)xdbl)[i] = s;
}

// ======== fused chunked selective scan: one block per chain ===================
// 256 threads = 4 waves; wave-local chunks (no barriers in main loops);
// delta/u read as bf16x8 (2 loads / 16 steps); B/C scalar coalesced fp32.
// a computed inline from A_log (aneg kernel removed).
__global__ __launch_bounds__(256) void scan_f_k(const __bf16* __restrict__ delta,
    const __bf16* __restrict__ u, const float* __restrict__ xdbl,
    const float* __restrict__ A_log, __bf16* __restrict__ y)
{
    __shared__ float combA[NCHUNK][16];
    __shared__ float combS[NCHUNK][16];
    __shared__ float sins[NCHUNK][16];
    __shared__ float lp[NCHUNK][16][17];
    const int tid = threadIdx.x;
    const int lane = tid & 63;
    const int n = lane & 15;
    const int c = (tid >> 6) * 4 + (lane >> 4);   // wave-local chunk id
    const int g = blockIdx.x;                     // chain id = b*D_INNER + d
    const int b = g >> 11, d = g & (D_INNER - 1);
    const float a = -__expf(A_log[d * D_STATE + n]);
    const long long base = (long long)g * SEQLEN + c * CHUNK;
    const bf16x8* dv = (const bf16x8*)(delta + base);
    const bf16x8* uv = (const bf16x8*)(u + base);
    const float* xb = xdbl + ((long long)b * SEQLEN + c * CHUNK) * XSTR + DT_RANK + n;

    // ---- pass 1: chunk-local scan from 0, accumulate A = prod dA ----
    bf16x8 pd[2], pu[2];
    float pB[16];
    pd[0] = dv[0]; pd[1] = dv[1];
    pu[0] = uv[0]; pu[1] = uv[1];
    #pragma unroll
    for (int i = 0; i < 16; ++i) pB[i] = xb[i * XSTR];

    float s = 0.f, ap = 1.f;
    for (int t0 = 0; t0 < CHUNK; t0 += 16) {
        float cd[16], cu[16], cB[16];
        #pragma unroll
        for (int i = 0; i < 16; ++i) {
            cd[i] = (float)pd[i >> 3][i & 7];
            cu[i] = (float)pu[i >> 3][i & 7];
            cB[i] = pB[i];
        }
        if (t0 + 16 < CHUNK) {
            const int nb = (t0 >> 3) + 2;
            pd[0] = dv[nb]; pd[1] = dv[nb + 1];
            pu[0] = uv[nb]; pu[1] = uv[nb + 1];
            const float* xn = xb + (t0 + 16) * XSTR;
            #pragma unroll
            for (int i = 0; i < 16; ++i) pB[i] = xn[i * XSTR];
        }
        float dA[16], wB[16];
        #pragma unroll
        for (int i = 0; i < 16; ++i) {
            dA[i] = __expf(cd[i] * a);
            wB[i] = cd[i] * cu[i] * cB[i];
        }
        #pragma unroll
        for (int i = 0; i < 16; ++i) {
            s = dA[i] * s + wB[i];
            ap *= dA[i];
        }
    }
    combA[c][n] = ap;
    combS[c][n] = s;
    __syncthreads();

    // ---- combine: 16 threads do the serial 16-chunk prefix ----
    if (tid < 16) {
        float av[NCHUNK], sv[NCHUNK];
        #pragma unroll
        for (int cc = 0; cc < NCHUNK; ++cc) { av[cc] = combA[cc][tid]; sv[cc] = combS[cc][tid]; }
        float carry = 0.f;
        #pragma unroll
        for (int cc = 0; cc < NCHUNK; ++cc) {
            sins[cc][tid] = carry;
            carry = sv[cc] + av[cc] * carry;
        }
    }
    __syncthreads();

    // ---- pass 2: re-scan from sinit, emit y bf16 (no barriers) ----
    __bf16* yl = y + base;
    float pC[16];
    pd[0] = dv[0]; pd[1] = dv[1];
    pu[0] = uv[0]; pu[1] = uv[1];
    #pragma unroll
    for (int i = 0; i < 16; ++i) { pB[i] = xb[i * XSTR]; pC[i] = xb[i * XSTR + D_STATE]; }

    s = sins[c][n];
    for (int t0 = 0; t0 < CHUNK; t0 += 16) {
        float cd[16], cu[16], cB[16], cC[16];
        #pragma unroll
        for (int i = 0; i < 16; ++i) {
            cd[i] = (float)pd[i >> 3][i & 7];
            cu[i] = (float)pu[i >> 3][i & 7];
            cB[i] = pB[i];
            cC[i] = pC[i];
        }
        if (t0 + 16 < CHUNK) {
            const int nb = (t0 >> 3) + 2;
            pd[0] = dv[nb]; pd[1] = dv[nb + 1];
            pu[0] = uv[nb]; pu[1] = uv[nb + 1];
            const float* xn = xb + (t0 + 16) * XSTR;
            #pragma unroll
            for (int i = 0; i < 16; ++i) { pB[i] = xn[i * XSTR]; pC[i] = xn[i * XSTR + D_STATE]; }
        }
        float dA[16], wB[16];
        #pragma unroll
        for (int i = 0; i < 16; ++i) {
            dA[i] = __expf(cd[i] * a);
            wB[i] = cd[i] * cu[i] * cB[i];
        }
        #pragma unroll
        for (int i = 0; i < 16; ++i) {
            s = dA[i] * s + wB[i];
            lp[c][n][i] = s * cC[i];
        }
        // same-wave transpose-reduce (lgkmcnt-ordered, no barrier)
        float v[16];
        #pragma unroll
        for (int j = 0; j < 16; ++j) v[j] = lp[c][j][n];
        float acc = 0.f;
        #pragma unroll
        for (int j = 0; j < 16; ++j) acc += v[j];
        yl[t0 + n] = (__bf16)acc;
    }
}

// ------- S[b,l] = sum_d Dp[d]*u[b,l,d] from d-contiguous ut16 (no atomics) ----
__global__ __launch_bounds__(256) void ssum_k(const __bf16* __restrict__ ut,
    const float* __restrict__ Dp, float* __restrict__ S)
{
    __shared__ float part[8][33];
    const int tid = threadIdx.x;
    const int ls = tid >> 5;       // 0..7
    const int dg = tid & 31;       // 0..31
    const int li = blockIdx.x * 8 + ls;
    const bf16x8* row = (const bf16x8*)(ut + (long long)li * D_INNER) + dg * 8;
    float acc = 0.f;
    #pragma unroll
    for (int q = 0; q < 8; ++q) {
        bf16x8 v = row[q];
        #pragma unroll
        for (int j = 0; j < 8; ++j) acc += Dp[dg * 64 + q * 8 + j] * (float)v[j];
    }
    part[ls][dg] = acc;
    __syncthreads();
    if (tid < 8) {
        float s = 0.f;
        #pragma unroll
        for (int q = 0; q < 32; ++q) s += part[tid][q];
        S[blockIdx.x * 8 + tid] = s;
    }
}

// ---------------- y=(y+Dp*u)*silu(z), transposed into ycat16[...,:2048] -------
__global__ __launch_bounds__(256) void ytrans_k(const __bf16* __restrict__ ysc,
    const __bf16* __restrict__ u, const __bf16* __restrict__ xz,
    const float* __restrict__ Dp, __bf16* __restrict__ ycat)
{
    __shared__ float tile[32][33];
    const int b = blockIdx.z;
    const int d0 = blockIdx.y * 32, l0 = blockIdx.x * 32;
    const int lx = threadIdx.x, dy = threadIdx.y;
    #pragma unroll
    for (int j = 0; j < 4; ++j) {
        int d = d0 + dy + j * 8;
        long long i  = ((long long)b * D_INNER + d) * SEQLEN + l0 + lx;
        long long iz = ((long long)b * 2 * D_INNER + D_INNER + d) * SEQLEN + l0 + lx;
        tile[dy + j * 8][lx] = ((float)ysc[i] + Dp[d] * (float)u[i]) * silu_f((float)xz[iz]);
    }
    __syncthreads();
    #pragma unroll
    for (int j = 0; j < 4; ++j) {
        int l = l0 + dy + j * 8;
        ycat[((long long)b * SEQLEN + l) * (2 * D_INNER) + d0 + lx] = (__bf16)tile[lx][dy + j * 8];
    }
}

// ---------------- y_t -> ycat16[...,2048:]  (An computed from A_log) ----------
__global__ __launch_bounds__(256) void yt_k(const float* __restrict__ xdbl,
    const float* __restrict__ A_log, const float* __restrict__ S, __bf16* __restrict__ ycat)
{
    __shared__ float Cs[16][33];
    __shared__ float An[16][64];
    __shared__ float Sv[32];
    const int b = blockIdx.z;
    const int d0 = blockIdx.y * 64, l0 = blockIdx.x * 32;
    const int tid = threadIdx.x;
    for (int f = tid; f < 512; f += 256) {
        int n = f & 15, l = f >> 4;
        Cs[n][l] = xdbl[((long long)b * SEQLEN + l0 + l) * XSTR + DT_RANK + D_STATE + n];
    }
    for (int f = tid; f < 1024; f += 256) {
        int n = f & 15, d = f >> 4;
        An[n][d] = -__expf(A_log[(d0 + d) * D_STATE + n]);
    }
    if (tid < 32) Sv[tid] = S[b * SEQLEN + l0 + tid];
    __syncthreads();
    const int dx = tid & 63, lg = tid >> 6;
    #pragma unroll
    for (int j = 0; j < 8; ++j) {
        int l = lg * 8 + j;
        float acc = Sv[l];
        #pragma unroll
        for (int n = 0; n < 16; ++n) acc += Cs[n][l] * An[n][dx];
        ycat[((long long)b * SEQLEN + l0 + l) * (2 * D_INNER) + D_INNER + d0 + dx] = (__bf16)acc;
    }
}

extern "C" void kernel_launch(void* const* d_in, const int* in_sizes, int n_in,
                              void* d_out, int out_size, void* d_ws, size_t ws_size,
                              hipStream_t stream)
{
    const float* x      = (const float*)d_in[0];
    const float* W_in   = (const float*)d_in[1];
    const float* conv_w = (const float*)d_in[2];
    const float* conv_b = (const float*)d_in[3];
    const float* W_x    = (const float*)d_in[4];
    const float* W_dt   = (const float*)d_in[5];
    const float* b_dt   = (const float*)d_in[6];
    const float* A_log  = (const float*)d_in[7];
    const float* Dp     = (const float*)d_in[8];
    const float* W_out1 = (const float*)d_in[9];
    const float* W_out2 = (const float*)d_in[10];
    float* out = (float*)d_out;
    float* ws  = (float*)d_ws;

    // layout (floats unless noted)
    __bf16* xz16 = (__bf16*)ws;                    // 16777216 el (8388608 f)
    float* xdblp = ws + 8388608;                   //   524288 (B*L x 128)
    float* S     = xdblp + 524288;                 //     4096
    float* xpart = S + 4096;                       //  4194304 (8 x 524288)
    __bf16* u16    = (__bf16*)(xpart + 4194304);   //  8388608 el [b,d,l]
    __bf16* dtb16  = u16    + 8388608;             //  8388608 el (delta)
    __bf16* ysc16  = dtb16  + 8388608;             //  8388608 el
    __bf16* ycat16 = ysc16  + 8388608;             // 16777216 el
    __bf16* h16    = ycat16 + 16777216;            //  8388608 el
    __bf16* Wout116= h16    + 8388608;             //  8388608 el
    __bf16* Wout216= Wout116+ 8388608;             //  2097152 el
    // overlays (regions dead at time of use)
    __bf16* W_in16 = u16;                          // before conv writes u16
    __bf16* xb16   = W_in16 + 4194304;
    __bf16* ut16   = ycat16;                       // before ytrans/yt write ycat
    __bf16* Wx16p  = h16;                          // before out1 writes h16

    // fused front conversions (W_in, x, Wx + pad): 1081344 g8 -> 4224 blocks
    cvt_front_k<<<4224, 256, 0, stream>>>(W_in, x, W_x, W_in16, xb16, Wx16p);

    // xz[b,e,l] = sum_d W_in[e,d] * x[b,l,d] -> bf16  (M=4096, N=2048, K=1024)
    gemm_bf16_k<0, 1><<<dim3(16, 32, BATCH), 256, 0, stream>>>(
        W_in16, xb16, xz16, D_MODEL, D_MODEL, D_MODEL, SEQLEN,
        0LL, (long long)SEQLEN * D_MODEL, (long long)4096 * SEQLEN);

    conv_silu_k<<<dim3(SEQLEN / 32, D_INNER / 32, BATCH), dim3(32, 8), 0, stream>>>(
        xz16, conv_w, conv_b, u16, ut16);

    // x_dbl partials: K-split=8 (z selects k-range via sA/sB), 256 blocks
    gemm_bf16_k<0, 0><<<dim3(1, 32, XKS), 256, 0, stream>>>(
        ut16, Wx16p, xpart, D_INNER / XKS, D_INNER, D_INNER, XSTR,
        (long long)(D_INNER / XKS), (long long)(D_INNER / XKS),
        (long long)BATCH * SEQLEN * XSTR);
    xdbl_red_k<<<(BATCH * SEQLEN * XSTR / 4) / 256, 256, 0, stream>>>(xpart, xdblp);

    // dt = softplus(x_dbl @ W_dt^T + b_dt) -> bf16   (fused epilogue)
    gemm_nt_k<1, 1><<<dim3(SEQLEN / 64, D_INNER / 64, BATCH), 256, 0, stream>>>(
        W_dt, xdblp, dtb16, b_dt, D_INNER, SEQLEN, DT_RANK, DT_RANK, XSTR, SEQLEN,
        0LL, (long long)SEQLEN * XSTR, (long long)D_INNER * SEQLEN);

    // fused chunked scan: one block per chain, bf16 in/out; a from A_log inline
    scan_f_k<<<BATCH * D_INNER, 256, 0, stream>>>(dtb16, u16, xdblp, A_log, ysc16);

    // fused back conversions (W_out1, W_out2): 1310720 g8 -> 5120 blocks
    cvt_back_k<<<5120, 256, 0, stream>>>(W_out1, W_out2, Wout116, Wout216);

    ssum_k<<<(BATCH * SEQLEN) / 8, 256, 0, stream>>>(ut16, Dp, S);

    ytrans_k<<<dim3(SEQLEN / 32, D_INNER / 32, BATCH), dim3(32, 8), 0, stream>>>(ysc16, u16, xz16, Dp, ycat16);

    yt_k<<<dim3(SEQLEN / 32, D_INNER / 64, BATCH), 256, 0, stream>>>(xdblp, A_log, S, ycat16);

    // h = relu(ycat @ W_out1^T) -> bf16   (M=4096, N=2048, K=4096)
    gemm_bf16_k<1, 1><<<dim3(16, 32, 1), 256, 0, stream>>>(
        ycat16, Wout116, h16, 2 * D_INNER, 2 * D_INNER, 2 * D_INNER, D_INNER,
        0LL, 0LL, 0LL);

    // out = h @ W_out2^T   (M=4096, N=1024, K=2048)
    gemm_bf16_k<0, 0><<<dim3(8, 32, 1), 256, 0, stream>>>(
        h16, Wout216, out, D_INNER, D_INNER, D_INNER, D_MODEL,
        0LL, 0LL, 0LL);
}